// Round 8
// baseline (690.601 us; speedup 1.0000x reference)
//
#include <hip/hip_runtime.h>
#include <hip/hip_bf16.h>

// ---------------------------------------------------------------------------
// DeepSGC on MI355X:
//   - CSR build per call: rank-recording deg pass, 2-kernel scan, atomic-free fill
//   - ALL hop gathers int16 row-quantized (128-wide: 256B/row; 40-wide: 80B/row)
//     with per-row scale S (dequant) and Sn = S*norm (fuses the norm gather-scale)
//   - hop pairs folded: k1: z = N^2 A (Sn-scaled gather); k2: y = N A z
//   - dense layers via 3x bf16 MFMA split-precision (hi+lo), ~fp32-exact
//   - layer-3 reorder: project 128->40 first, then 2 hops at 40-wide
// ---------------------------------------------------------------------------

typedef __attribute__((ext_vector_type(8))) short short8v;   // 8 x bf16
typedef __attribute__((ext_vector_type(4))) float f32x4;
typedef __attribute__((ext_vector_type(2))) unsigned int u32x2;

#define SBLK 128  // scan segments

__device__ __forceinline__ unsigned short f2bf(float x) {
    unsigned int u = __builtin_bit_cast(unsigned int, x);
    unsigned int r = u + 0x7fffu + ((u >> 16) & 1u);   // RNE
    return (unsigned short)(r >> 16);
}
__device__ __forceinline__ float bf2f(unsigned short h) {
    unsigned int u = ((unsigned int)h) << 16;
    return __builtin_bit_cast(float, u);
}

// ------------------------------- CSR build --------------------------------

__global__ void __launch_bounds__(256) deg_rank_kernel(const int* __restrict__ dst,
                                                       int* __restrict__ deg,
                                                       int* __restrict__ rank, int E) {
    int e = blockIdx.x * blockDim.x + threadIdx.x;
    if (e < E) rank[e] = atomicAdd(&deg[dst[e]], 1);
}

__global__ void __launch_bounds__(256) scanA_kernel(const int* __restrict__ deg,
                                                    int* __restrict__ rowptr,
                                                    int* __restrict__ bsum,
                                                    float* __restrict__ norm,
                                                    int n, int seg) {
    __shared__ int ws[4];
    __shared__ int carry;
    int b = blockIdx.x;
    int start = b * seg;
    int finish = start + seg; if (finish > n) finish = n;
    int t = threadIdx.x, lane = t & 63, w = t >> 6;
    if (t == 0) carry = 0;
    __syncthreads();
    for (int base = start; base < finish; base += 256) {
        int i = base + t;
        int v = 0;
        if (i < finish) {
            v = deg[i];
            norm[i] = rsqrtf((float)(v < 1 ? 1 : v));
        }
        int x = v;
        #pragma unroll
        for (int off = 1; off < 64; off <<= 1) {
            int y = __shfl_up(x, off, 64);
            if (lane >= off) x += y;
        }
        if (lane == 63) ws[w] = x;
        __syncthreads();
        int woff = 0;
        #pragma unroll
        for (int k = 0; k < 4; ++k) if (k < w) woff += ws[k];
        if (i < finish) rowptr[i] = carry + woff + x - v;
        int tot = ws[0] + ws[1] + ws[2] + ws[3];
        __syncthreads();
        if (t == 0) carry += tot;
        __syncthreads();
    }
    if (t == 0) bsum[b] = carry;
}

__global__ void __launch_bounds__(256) scanC_kernel(int* __restrict__ rowptr,
                                                    const int* __restrict__ bsum,
                                                    int n, int seg) {
    __shared__ int tmp[SBLK + 1];
    int b = blockIdx.x, t = threadIdx.x;
    if (t < SBLK) tmp[t] = bsum[t];
    __syncthreads();
    if (t == 0) {
        int s = 0;
        #pragma unroll 4
        for (int i = 0; i < SBLK; ++i) { int v = tmp[i]; tmp[i] = s; s += v; }
        tmp[SBLK] = s;
    }
    __syncthreads();
    int add = tmp[b];
    int start = b * seg;
    int finish = start + seg; if (finish > n) finish = n;
    for (int i = start + t; i < finish; i += 256) rowptr[i] += add;
    if (b == 0 && t == 0) rowptr[n] = tmp[SBLK];
}

__global__ void __launch_bounds__(256) fill_kernel(const int* __restrict__ src,
                                                   const int* __restrict__ dst,
                                                   const int* __restrict__ rowptr,
                                                   const int* __restrict__ rank,
                                                   int* __restrict__ col, int E) {
    int e = blockIdx.x * blockDim.x + threadIdx.x;
    if (e < E) col[rowptr[dst[e]] + rank[e]] = src[e];
}

// ------------------------ input row quantization ---------------------------

__global__ void __launch_bounds__(256) xquant_kernel(const float4* __restrict__ x,
                                                     const float* __restrict__ norm,
                                                     u32x2* __restrict__ xq,
                                                     float* __restrict__ Sn,
                                                     int n) {
    int gw = (blockIdx.x * blockDim.x + threadIdx.x) >> 6;
    int lane = threadIdx.x & 63, half = lane >> 5, l32 = lane & 31;
    int node = gw * 2 + half;
    if (node >= n) return;
    float4 v = x[(size_t)node * 32 + l32];
    float m = fmaxf(fmaxf(fabsf(v.x), fabsf(v.y)), fmaxf(fabsf(v.z), fabsf(v.w)));
    #pragma unroll
    for (int s = 1; s < 32; s <<= 1) m = fmaxf(m, __shfl_xor(m, s));
    float sraw = fmaxf(m, 1e-30f);
    float inv = 32767.f / sraw;
    float sv = sraw * (1.f / 32767.f);
    int a0 = (int)rintf(fminf(fmaxf(v.x * inv, -32767.f), 32767.f));
    int a1 = (int)rintf(fminf(fmaxf(v.y * inv, -32767.f), 32767.f));
    int a2 = (int)rintf(fminf(fmaxf(v.z * inv, -32767.f), 32767.f));
    int a3 = (int)rintf(fminf(fmaxf(v.w * inv, -32767.f), 32767.f));
    u32x2 p = {(unsigned)(a0 & 0xffff) | ((unsigned)a1 << 16),
               (unsigned)(a2 & 0xffff) | ((unsigned)a3 << 16)};
    __builtin_nontemporal_store(p, &xq[(size_t)node * 32 + l32]);
    if (l32 == 0) Sn[node] = sv * norm[node];
}

// --------------------------- 128-wide SpMM hops ----------------------------
// int16 gather: row = 32 x u32x2 (8B/lane, half-wave/row). 16 edges in
// flight per iter (8 per half-wave). esc = Sn (k1) or S (k2).

template <int EPI>  // 0: int16 quant out + S [k1]; 1: Hi/Lo bf16 split out [k2]
__global__ void __launch_bounds__(256) spmm128_q(const u32x2* __restrict__ hq,
                                                 const float* __restrict__ esc,
                                                 const int* __restrict__ rp,
                                                 const int* __restrict__ col,
                                                 const float* __restrict__ norm,
                                                 u32x2* __restrict__ outq,
                                                 float* __restrict__ So,
                                                 u32x2* __restrict__ Hi,
                                                 u32x2* __restrict__ Lo,
                                                 int n) {
    int wid = (blockIdx.x * blockDim.x + threadIdx.x) >> 6;
    if (wid >= n) return;
    int lane = threadIdx.x & 63, half = lane >> 5, l32 = lane & 31;
    int beg = rp[wid], end = rp[wid + 1];
    f32x4 acc = {0.f, 0.f, 0.f, 0.f};
    if (beg < end) {
        int last = end - 1;
        for (int e = beg; e < end; e += 16) {
            float s[8];
            u32x2 q[8];
            #pragma unroll
            for (int k = 0; k < 8; ++k) {
                int i = e + 2 * k + half;
                int ic = i < end ? i : last;
                int u = col[ic];
                s[k] = i < end ? esc[u] : 0.f;
                q[k] = hq[(size_t)u * 32 + l32];
            }
            #pragma unroll
            for (int k = 0; k < 8; ++k) {
                acc.x += (float)(short)(q[k].x) * s[k];
                acc.y += (float)((int)q[k].x >> 16) * s[k];
                acc.z += (float)(short)(q[k].y) * s[k];
                acc.w += (float)((int)q[k].y >> 16) * s[k];
            }
        }
    }
    acc.x += __shfl_xor(acc.x, 32);
    acc.y += __shfl_xor(acc.y, 32);
    acc.z += __shfl_xor(acc.z, 32);
    acc.w += __shfl_xor(acc.w, 32);
    float nv = norm[wid];
    if (EPI == 0) {
        float f = nv * nv;
        acc.x *= f; acc.y *= f; acc.z *= f; acc.w *= f;
        float m = fmaxf(fmaxf(fabsf(acc.x), fabsf(acc.y)), fmaxf(fabsf(acc.z), fabsf(acc.w)));
        #pragma unroll
        for (int s = 1; s < 64; s <<= 1) m = fmaxf(m, __shfl_xor(m, s));
        float sraw = fmaxf(m, 1e-30f);
        float inv = 32767.f / sraw;
        float sv = sraw * (1.f / 32767.f);
        if (half == 0) {
            int a0 = (int)rintf(fminf(fmaxf(acc.x * inv, -32767.f), 32767.f));
            int a1 = (int)rintf(fminf(fmaxf(acc.y * inv, -32767.f), 32767.f));
            int a2 = (int)rintf(fminf(fmaxf(acc.z * inv, -32767.f), 32767.f));
            int a3 = (int)rintf(fminf(fmaxf(acc.w * inv, -32767.f), 32767.f));
            u32x2 p = {(unsigned)(a0 & 0xffff) | ((unsigned)a1 << 16),
                       (unsigned)(a2 & 0xffff) | ((unsigned)a3 << 16)};
            __builtin_nontemporal_store(p, &outq[(size_t)wid * 32 + l32]);
        }
        if (lane == 0) So[wid] = sv;
    } else {
        if (half == 0) {
            float v0 = acc.x * nv, v1 = acc.y * nv, v2 = acc.z * nv, v3 = acc.w * nv;
            unsigned short h0 = f2bf(v0), h1 = f2bf(v1), h2 = f2bf(v2), h3 = f2bf(v3);
            unsigned short l0 = f2bf(v0 - bf2f(h0)), l1 = f2bf(v1 - bf2f(h1));
            unsigned short l2 = f2bf(v2 - bf2f(h2)), l3 = f2bf(v3 - bf2f(h3));
            u32x2 hp = {(unsigned int)h0 | ((unsigned int)h1 << 16),
                        (unsigned int)h2 | ((unsigned int)h3 << 16)};
            u32x2 lp = {(unsigned int)l0 | ((unsigned int)l1 << 16),
                        (unsigned int)l2 | ((unsigned int)l3 << 16)};
            __builtin_nontemporal_store(hp, &Hi[(size_t)wid * 32 + l32]);
            __builtin_nontemporal_store(lp, &Lo[(size_t)wid * 32 + l32]);
        }
    }
}

// ---------------------------- 40-wide SpMM hops ----------------------------
// int16 rows: 40 int16 = 10 x u32x2 per row (lane t holds elements 4t..4t+3).
// 6 edge-slots x 10 lanes, 18 edges in flight.

template <int EPI>  // 0: hop1 (esc=Sn3, f=nv^2, int16 out + S4); 1: hop2 (esc=S4, f=nv, f32 out + b3)
__global__ void __launch_bounds__(256) spmm40_q(const u32x2* __restrict__ hq,
                                                const float* __restrict__ esc,
                                                const int* __restrict__ rp,
                                                const int* __restrict__ col,
                                                const float* __restrict__ norm,
                                                u32x2* __restrict__ outq,
                                                float* __restrict__ So,
                                                f32x4* __restrict__ outf,
                                                const float* __restrict__ b3,
                                                int n) {
    int wid = (blockIdx.x * blockDim.x + threadIdx.x) >> 6;
    if (wid >= n) return;
    int lane = threadIdx.x & 63;
    int slot = lane / 10;      // 0..5 active; lanes 60-63 idle
    int t = lane % 10;
    bool active = slot < 6;
    int beg = rp[wid], end = rp[wid + 1];
    f32x4 acc = {0.f, 0.f, 0.f, 0.f};
    if (beg < end) {
        int last = end - 1;
        for (int base = beg; base < end; base += 18) {
            float s[3];
            u32x2 q[3];
            #pragma unroll
            for (int k = 0; k < 3; ++k) {
                int i = base + 6 * k + slot;
                int ic = (active && i < end) ? i : last;
                int u = col[ic];
                s[k] = (active && i < end) ? esc[u] : 0.f;
                q[k] = hq[(size_t)u * 10 + t];
            }
            #pragma unroll
            for (int k = 0; k < 3; ++k) {
                acc.x += (float)(short)(q[k].x) * s[k];
                acc.y += (float)((int)q[k].x >> 16) * s[k];
                acc.z += (float)(short)(q[k].y) * s[k];
                acc.w += (float)((int)q[k].y >> 16) * s[k];
            }
        }
    }
    // cross-slot total (valid for lanes with slot<6; slot 6 partial)
    f32x4 tot = acc;
    #pragma unroll
    for (int k = 1; k < 6; ++k) {
        int srcl = t + ((slot + k) % 6) * 10;
        tot.x += __shfl(acc.x, srcl);
        tot.y += __shfl(acc.y, srcl);
        tot.z += __shfl(acc.z, srcl);
        tot.w += __shfl(acc.w, srcl);
    }
    float nv = norm[wid];
    if (EPI == 0) {
        float f = nv * nv;
        f32x4 v = {tot.x * f, tot.y * f, tot.z * f, tot.w * f};
        float m = (slot < 6)
                ? fmaxf(fmaxf(fabsf(v.x), fabsf(v.y)), fmaxf(fabsf(v.z), fabsf(v.w)))
                : 0.f;
        #pragma unroll
        for (int s = 1; s < 64; s <<= 1) m = fmaxf(m, __shfl_xor(m, s));
        float sraw = fmaxf(m, 1e-30f);
        float inv = 32767.f / sraw;
        float sv = sraw * (1.f / 32767.f);
        if (slot == 0) {
            int a0 = (int)rintf(fminf(fmaxf(v.x * inv, -32767.f), 32767.f));
            int a1 = (int)rintf(fminf(fmaxf(v.y * inv, -32767.f), 32767.f));
            int a2 = (int)rintf(fminf(fmaxf(v.z * inv, -32767.f), 32767.f));
            int a3 = (int)rintf(fminf(fmaxf(v.w * inv, -32767.f), 32767.f));
            u32x2 p = {(unsigned)(a0 & 0xffff) | ((unsigned)a1 << 16),
                       (unsigned)(a2 & 0xffff) | ((unsigned)a3 << 16)};
            __builtin_nontemporal_store(p, &outq[(size_t)wid * 10 + t]);
        }
        if (lane == 0) So[wid] = sv;
    } else {
        if (slot == 0) {
            f32x4 bv = ((const f32x4*)b3)[t];
            f32x4 o = {tot.x * nv + bv.x, tot.y * nv + bv.y,
                       tot.z * nv + bv.z, tot.w * nv + bv.w};
            __builtin_nontemporal_store(o, &outf[(size_t)wid * 10 + t]);
        }
    }
}

// ------------------------- W fragment preparation --------------------------

__device__ __forceinline__ void wprep_one(const float* __restrict__ W,
                                          short* __restrict__ Wh,
                                          short* __restrict__ Wl,
                                          int ncols, int CF, int i) {
    int j = i & 7;
    int lane = (i >> 3) & 63;
    int f = i >> 9;
    int cf = f % CF, ks = f / CF;
    int k = ks * 32 + 8 * (lane >> 4) + j;
    int c = cf * 16 + (lane & 15);
    float v = (c < ncols) ? W[k * ncols + c] : 0.f;
    unsigned short h = f2bf(v);
    unsigned short l = f2bf(v - bf2f(h));
    Wh[i] = (short)h;
    Wl[i] = (short)l;
}

__global__ void __launch_bounds__(256) wprep_all(const float* __restrict__ W1,
                                                 const float* __restrict__ W2,
                                                 const float* __restrict__ W3,
                                                 short* __restrict__ W1h, short* __restrict__ W1l,
                                                 short* __restrict__ W2h, short* __restrict__ W2l,
                                                 short* __restrict__ W3h, short* __restrict__ W3l) {
    int i = blockIdx.x * blockDim.x + threadIdx.x;
    if (i < 16384) wprep_one(W1, W1h, W1l, 128, 8, i);
    else if (i < 32768) wprep_one(W2, W2h, W2l, 128, 8, i - 16384);
    else if (i < 38912) wprep_one(W3, W3h, W3l, 40, 3, i - 32768);
}

// ------------------------- split-bf16 MFMA GEMMs ---------------------------
// 128->128: A from Hi/Lo bf16; out = relu(AW+b) int16-quantized + S (+Sn).

__global__ void __launch_bounds__(256) gemm_mfma128(const unsigned short* __restrict__ Ahi,
                                                    const unsigned short* __restrict__ Alo,
                                                    const short8v* __restrict__ Wh,
                                                    const short8v* __restrict__ Wl,
                                                    const float* __restrict__ bias,
                                                    const float* __restrict__ norm,
                                                    unsigned short* __restrict__ Cq,
                                                    float* __restrict__ So,
                                                    float* __restrict__ Sno,
                                                    int n) {
    int lane = threadIdx.x & 63;
    int wid = threadIdx.x >> 6;
    int r0 = blockIdx.x * 64 + wid * 16;
    if (r0 >= n) return;
    int arow = r0 + (lane & 15);
    if (arow > n - 1) arow = n - 1;
    int kbase = 8 * (lane >> 4);
    f32x4 acc[8];
    #pragma unroll
    for (int i = 0; i < 8; ++i) acc[i] = (f32x4){0.f, 0.f, 0.f, 0.f};
    #pragma unroll
    for (int ks = 0; ks < 4; ++ks) {
        short8v ah = *(const short8v*)(Ahi + (size_t)arow * 128 + ks * 32 + kbase);
        short8v al = *(const short8v*)(Alo + (size_t)arow * 128 + ks * 32 + kbase);
        #pragma unroll
        for (int cf = 0; cf < 8; ++cf) {
            short8v bh = Wh[(ks * 8 + cf) * 64 + lane];
            short8v bl = Wl[(ks * 8 + cf) * 64 + lane];
            acc[cf] = __builtin_amdgcn_mfma_f32_16x16x32_bf16(ah, bh, acc[cf], 0, 0, 0);
            acc[cf] = __builtin_amdgcn_mfma_f32_16x16x32_bf16(al, bh, acc[cf], 0, 0, 0);
            acc[cf] = __builtin_amdgcn_mfma_f32_16x16x32_bf16(ah, bl, acc[cf], 0, 0, 0);
        }
    }
    int rbase = r0 + (lane >> 4) * 4;
    int c0 = lane & 15;
    float bc[8];
    #pragma unroll
    for (int cf = 0; cf < 8; ++cf) bc[cf] = bias[cf * 16 + c0];

    float mq[4] = {0.f, 0.f, 0.f, 0.f};
    #pragma unroll
    for (int cf = 0; cf < 8; ++cf) {
        #pragma unroll
        for (int q = 0; q < 4; ++q)
            mq[q] = fmaxf(mq[q], fmaxf(acc[cf][q] + bc[cf], 0.f));
    }
    #pragma unroll
    for (int s = 1; s < 16; s <<= 1) {
        #pragma unroll
        for (int q = 0; q < 4; ++q) mq[q] = fmaxf(mq[q], __shfl_xor(mq[q], s));
    }
    float invq[4], svq[4];
    #pragma unroll
    for (int q = 0; q < 4; ++q) {
        float sraw = fmaxf(mq[q], 1e-30f);
        invq[q] = 32767.f / sraw;
        svq[q] = sraw * (1.f / 32767.f);
    }
    #pragma unroll
    for (int cf = 0; cf < 8; ++cf) {
        int colc = cf * 16 + c0;
        #pragma unroll
        for (int q = 0; q < 4; ++q) {
            int row = rbase + q;
            if (row >= n) continue;
            float v = fmaxf(acc[cf][q] + bc[cf], 0.f);
            int qi = (int)rintf(fminf(v * invq[q], 32767.f));  // v >= 0
            Cq[(size_t)row * 128 + colc] = (unsigned short)qi;
        }
    }
    if (c0 == 0) {
        #pragma unroll
        for (int q = 0; q < 4; ++q) {
            int row = rbase + q;
            if (row < n) { So[row] = svq[q]; Sno[row] = svq[q] * norm[row]; }
        }
    }
}

// 128->40: A from int16+scale (in-register hi/lo split); out int16 + S3/Sn3.
__global__ void __launch_bounds__(256) gemm_mfma40(const unsigned short* __restrict__ Aq,
                                                   const float* __restrict__ SA,
                                                   const short8v* __restrict__ Wh,
                                                   const short8v* __restrict__ Wl,
                                                   const float* __restrict__ norm,
                                                   unsigned short* __restrict__ Cq,
                                                   float* __restrict__ S3,
                                                   float* __restrict__ Sn3,
                                                   int n) {
    int lane = threadIdx.x & 63;
    int wid = threadIdx.x >> 6;
    int r0 = blockIdx.x * 64 + wid * 16;
    if (r0 >= n) return;
    int arow = r0 + (lane & 15);
    if (arow > n - 1) arow = n - 1;
    int kbase = 8 * (lane >> 4);
    float sA = SA[arow];
    f32x4 acc[3];
    #pragma unroll
    for (int i = 0; i < 3; ++i) acc[i] = (f32x4){0.f, 0.f, 0.f, 0.f};
    #pragma unroll
    for (int ks = 0; ks < 4; ++ks) {
        short8v qv = *(const short8v*)(Aq + (size_t)arow * 128 + ks * 32 + kbase);
        short8v ah, al;
        #pragma unroll
        for (int j = 0; j < 8; ++j) {
            float v = (float)qv[j] * sA;
            unsigned int uv = __builtin_bit_cast(unsigned int, v);
            unsigned short hi = (unsigned short)(uv >> 16);      // trunc bf16
            float r = v - bf2f(hi);
            ah[j] = (short)hi;
            al[j] = (short)f2bf(r);
        }
        #pragma unroll
        for (int cf = 0; cf < 3; ++cf) {
            short8v bh = Wh[(ks * 3 + cf) * 64 + lane];
            short8v bl = Wl[(ks * 3 + cf) * 64 + lane];
            acc[cf] = __builtin_amdgcn_mfma_f32_16x16x32_bf16(ah, bh, acc[cf], 0, 0, 0);
            acc[cf] = __builtin_amdgcn_mfma_f32_16x16x32_bf16(al, bh, acc[cf], 0, 0, 0);
            acc[cf] = __builtin_amdgcn_mfma_f32_16x16x32_bf16(ah, bl, acc[cf], 0, 0, 0);
        }
    }
    int rbase = r0 + (lane >> 4) * 4;
    int c0 = lane & 15;
    // per-row absmax over valid cols
    float mq[4] = {0.f, 0.f, 0.f, 0.f};
    #pragma unroll
    for (int cf = 0; cf < 3; ++cf) {
        int colc = cf * 16 + c0;
        if (colc < 40) {
            #pragma unroll
            for (int q = 0; q < 4; ++q) mq[q] = fmaxf(mq[q], fabsf(acc[cf][q]));
        }
    }
    #pragma unroll
    for (int s = 1; s < 16; s <<= 1) {
        #pragma unroll
        for (int q = 0; q < 4; ++q) mq[q] = fmaxf(mq[q], __shfl_xor(mq[q], s));
    }
    float invq[4], svq[4];
    #pragma unroll
    for (int q = 0; q < 4; ++q) {
        float sraw = fmaxf(mq[q], 1e-30f);
        invq[q] = 32767.f / sraw;
        svq[q] = sraw * (1.f / 32767.f);
    }
    #pragma unroll
    for (int cf = 0; cf < 3; ++cf) {
        int colc = cf * 16 + c0;
        if (colc >= 40) continue;
        #pragma unroll
        for (int q = 0; q < 4; ++q) {
            int row = rbase + q;
            if (row >= n) continue;
            float v = acc[cf][q];
            int qi = (int)rintf(fminf(fmaxf(v * invq[q], -32767.f), 32767.f));
            Cq[(size_t)row * 40 + colc] = (unsigned short)qi;
        }
    }
    if (c0 == 0) {
        #pragma unroll
        for (int q = 0; q < 4; ++q) {
            int row = rbase + q;
            if (row < n) { S3[row] = svq[q]; Sn3[row] = svq[q] * norm[row]; }
        }
    }
}

// --------------------------------- launch ----------------------------------

extern "C" void kernel_launch(void* const* d_in, const int* in_sizes, int n_in,
                              void* d_out, int out_size, void* d_ws, size_t ws_size,
                              hipStream_t stream) {
    const float* features = (const float*)d_in[0];
    const int*   src      = (const int*)d_in[1];
    const int*   dst      = (const int*)d_in[2];
    const float* W1 = (const float*)d_in[3];
    const float* b1 = (const float*)d_in[4];
    const float* W2 = (const float*)d_in[5];
    const float* b2 = (const float*)d_in[6];
    const float* W3 = (const float*)d_in[7];
    const float* b3 = (const float*)d_in[8];
    float* out = (float*)d_out;

    const int N = in_sizes[0] / 128;
    const int E = in_sizes[1];

    char* ws = (char*)d_ws;
    size_t off = 0;
    auto alloc = [&](size_t bytes) -> void* {
        void* p = ws + off;
        off += (bytes + 511) & ~(size_t)511;
        return p;
    };
    // int16 feature buffers [N][128] (25.6 MB each)
    u32x2* QA = (u32x2*)alloc((size_t)N * 32 * sizeof(u32x2));
    u32x2* QB = (u32x2*)alloc((size_t)N * 32 * sizeof(u32x2));
    unsigned short* Hi = (unsigned short*)alloc((size_t)N * 128 * sizeof(unsigned short));
    unsigned short* Lo = (unsigned short*)alloc((size_t)N * 128 * sizeof(unsigned short));
    // scales
    float* Snx = (float*)alloc((size_t)N * sizeof(float));  // producer Sn feeding k1
    float* Sk  = (float*)alloc((size_t)N * sizeof(float));  // k1 output S
    float* Sg  = (float*)alloc((size_t)N * sizeof(float));  // gemm128 output S
    float* Sng = (float*)alloc((size_t)N * sizeof(float));  // gemm128 output Sn
    float* S3  = (float*)alloc((size_t)N * sizeof(float));  // g40 output S
    float* Sn3 = (float*)alloc((size_t)N * sizeof(float));  // g40 output Sn
    float* S4  = (float*)alloc((size_t)N * sizeof(float));  // hop1-40 output S
    int*   col    = (int*)alloc((size_t)E * sizeof(int));
    int*   deg    = (int*)alloc((size_t)N * sizeof(int));
    int*   rowptr = (int*)alloc((size_t)(N + 1) * sizeof(int));
    float* norm   = (float*)alloc((size_t)N * sizeof(float));
    int*   bsum   = (int*)alloc((size_t)(SBLK + 2) * sizeof(int));
    short* W1h = (short*)alloc(16384 * sizeof(short));
    short* W1l = (short*)alloc(16384 * sizeof(short));
    short* W2h = (short*)alloc(16384 * sizeof(short));
    short* W2l = (short*)alloc(16384 * sizeof(short));
    short* W3h = (short*)alloc(6144 * sizeof(short));
    short* W3l = (short*)alloc(6144 * sizeof(short));
    // aliases: rank -> Hi (dead until k2 writes); G40 buffers -> QB / Hi (dead)
    int*   rank = (int*)Hi;
    u32x2* G1 = (u32x2*)QB;   // [N][10] u32x2 int16 (8 MB), QB dead after k2'
    u32x2* G2 = (u32x2*)Hi;   // Hi dead after g2

    const int seg = (N + SBLK - 1) / SBLK;
    const int eblocks = (E + 255) / 256;

    // --- CSR build ---
    hipMemsetAsync(deg, 0, (size_t)N * sizeof(int), stream);
    deg_rank_kernel<<<eblocks, 256, 0, stream>>>(dst, deg, rank, E);
    scanA_kernel<<<SBLK, 256, 0, stream>>>(deg, rowptr, bsum, norm, N, seg);
    scanC_kernel<<<SBLK, 256, 0, stream>>>(rowptr, bsum, N, seg);
    fill_kernel<<<eblocks, 256, 0, stream>>>(src, dst, rowptr, rank, col, E);

    // --- W fragment prep + input quantization ---
    wprep_all<<<(38912 + 255) / 256, 256, 0, stream>>>(W1, W2, W3, W1h, W1l, W2h, W2l, W3h, W3l);
    {
        int waves2 = (N + 1) / 2;
        int xblocks = (waves2 * 64 + 255) / 256;
        xquant_kernel<<<xblocks, 256, 0, stream>>>((const float4*)features, norm, QA, Snx, N);
    }

    const int spmm_blocks = (N * 64 + 255) / 256;  // one wave per node
    const int gemm_blocks = (N + 63) / 64;

    // layer 1
    spmm128_q<0><<<spmm_blocks, 256, 0, stream>>>(QA, Snx, rowptr, col, norm,
                                                  QB, Sk, nullptr, nullptr, N);
    spmm128_q<1><<<spmm_blocks, 256, 0, stream>>>(QB, Sk, rowptr, col, norm,
                                                  nullptr, nullptr, (u32x2*)Hi, (u32x2*)Lo, N);
    gemm_mfma128<<<gemm_blocks, 256, 0, stream>>>(Hi, Lo, (const short8v*)W1h, (const short8v*)W1l,
                                                  b1, norm, (unsigned short*)QA, Sg, Sng, N);

    // layer 2
    spmm128_q<0><<<spmm_blocks, 256, 0, stream>>>(QA, Sng, rowptr, col, norm,
                                                  QB, Sk, nullptr, nullptr, N);
    spmm128_q<1><<<spmm_blocks, 256, 0, stream>>>(QB, Sk, rowptr, col, norm,
                                                  nullptr, nullptr, (u32x2*)Hi, (u32x2*)Lo, N);
    gemm_mfma128<<<gemm_blocks, 256, 0, stream>>>(Hi, Lo, (const short8v*)W2h, (const short8v*)W2l,
                                                  b2, norm, (unsigned short*)QA, Sg, Sng, N);

    // layer 3 (reordered): project 128->40 (int16 in/out), then 2 hops at 40-wide
    gemm_mfma40<<<gemm_blocks, 256, 0, stream>>>((const unsigned short*)QA, Sg,
                                                 (const short8v*)W3h, (const short8v*)W3l,
                                                 norm, (unsigned short*)G1, S3, Sn3, N);
    spmm40_q<0><<<spmm_blocks, 256, 0, stream>>>(G1, Sn3, rowptr, col, norm,
                                                 G2, S4, nullptr, nullptr, N);
    spmm40_q<1><<<spmm_blocks, 256, 0, stream>>>(G2, S4, rowptr, col, norm,
                                                 nullptr, nullptr, (f32x4*)out, b3, N);
}

// Round 9
// 636.072 us; speedup vs baseline: 1.0857x; 1.0857x over previous
//
#include <hip/hip_runtime.h>
#include <hip/hip_bf16.h>

// ---------------------------------------------------------------------------
// DeepSGC on MI355X:
//   - CSR build per call: rank-recording deg pass, 2-kernel scan, atomic-free fill
//   - ALL hop gathers int16 row-quantized (128-wide: 256B/row; 40-wide: 80B/row)
//     with per-row scale S (dequant) and Sn = S*norm (fuses the norm gather-scale)
//   - hop pairs folded: k1: z = N^2 A (Sn-scaled gather); k2: y = N A z
//   - 128-wide SpMM: unroll 8 interleaved (measured-best: VGPR 24, occ 73%)
//   - dense layers via 3x bf16 MFMA split-precision (hi+lo), ~fp32-exact
//   - layer-3 reorder: project 128->40 first, then 2 hops at 40-wide
// ---------------------------------------------------------------------------

typedef __attribute__((ext_vector_type(8))) short short8v;   // 8 x bf16
typedef __attribute__((ext_vector_type(4))) float f32x4;
typedef __attribute__((ext_vector_type(2))) unsigned int u32x2;

#define SBLK 128  // scan segments

__device__ __forceinline__ unsigned short f2bf(float x) {
    unsigned int u = __builtin_bit_cast(unsigned int, x);
    unsigned int r = u + 0x7fffu + ((u >> 16) & 1u);   // RNE
    return (unsigned short)(r >> 16);
}
__device__ __forceinline__ float bf2f(unsigned short h) {
    unsigned int u = ((unsigned int)h) << 16;
    return __builtin_bit_cast(float, u);
}

// ------------------------------- CSR build --------------------------------

__global__ void __launch_bounds__(256) deg_rank_kernel(const int* __restrict__ dst,
                                                       int* __restrict__ deg,
                                                       int* __restrict__ rank, int E) {
    int e = blockIdx.x * blockDim.x + threadIdx.x;
    if (e < E) rank[e] = atomicAdd(&deg[dst[e]], 1);
}

__global__ void __launch_bounds__(256) scanA_kernel(const int* __restrict__ deg,
                                                    int* __restrict__ rowptr,
                                                    int* __restrict__ bsum,
                                                    float* __restrict__ norm,
                                                    int n, int seg) {
    __shared__ int ws[4];
    __shared__ int carry;
    int b = blockIdx.x;
    int start = b * seg;
    int finish = start + seg; if (finish > n) finish = n;
    int t = threadIdx.x, lane = t & 63, w = t >> 6;
    if (t == 0) carry = 0;
    __syncthreads();
    for (int base = start; base < finish; base += 256) {
        int i = base + t;
        int v = 0;
        if (i < finish) {
            v = deg[i];
            norm[i] = rsqrtf((float)(v < 1 ? 1 : v));
        }
        int x = v;
        #pragma unroll
        for (int off = 1; off < 64; off <<= 1) {
            int y = __shfl_up(x, off, 64);
            if (lane >= off) x += y;
        }
        if (lane == 63) ws[w] = x;
        __syncthreads();
        int woff = 0;
        #pragma unroll
        for (int k = 0; k < 4; ++k) if (k < w) woff += ws[k];
        if (i < finish) rowptr[i] = carry + woff + x - v;
        int tot = ws[0] + ws[1] + ws[2] + ws[3];
        __syncthreads();
        if (t == 0) carry += tot;
        __syncthreads();
    }
    if (t == 0) bsum[b] = carry;
}

__global__ void __launch_bounds__(256) scanC_kernel(int* __restrict__ rowptr,
                                                    const int* __restrict__ bsum,
                                                    int n, int seg) {
    __shared__ int tmp[SBLK + 1];
    int b = blockIdx.x, t = threadIdx.x;
    if (t < SBLK) tmp[t] = bsum[t];
    __syncthreads();
    if (t == 0) {
        int s = 0;
        #pragma unroll 4
        for (int i = 0; i < SBLK; ++i) { int v = tmp[i]; tmp[i] = s; s += v; }
        tmp[SBLK] = s;
    }
    __syncthreads();
    int add = tmp[b];
    int start = b * seg;
    int finish = start + seg; if (finish > n) finish = n;
    for (int i = start + t; i < finish; i += 256) rowptr[i] += add;
    if (b == 0 && t == 0) rowptr[n] = tmp[SBLK];
}

__global__ void __launch_bounds__(256) fill_kernel(const int* __restrict__ src,
                                                   const int* __restrict__ dst,
                                                   const int* __restrict__ rowptr,
                                                   const int* __restrict__ rank,
                                                   int* __restrict__ col, int E) {
    int e = blockIdx.x * blockDim.x + threadIdx.x;
    if (e < E) col[rowptr[dst[e]] + rank[e]] = src[e];
}

// ------------------------ input row quantization ---------------------------

__global__ void __launch_bounds__(256) xquant_kernel(const float4* __restrict__ x,
                                                     const float* __restrict__ norm,
                                                     u32x2* __restrict__ xq,
                                                     float* __restrict__ Sn,
                                                     int n) {
    int gw = (blockIdx.x * blockDim.x + threadIdx.x) >> 6;
    int lane = threadIdx.x & 63, half = lane >> 5, l32 = lane & 31;
    int node = gw * 2 + half;
    if (node >= n) return;
    float4 v = x[(size_t)node * 32 + l32];
    float m = fmaxf(fmaxf(fabsf(v.x), fabsf(v.y)), fmaxf(fabsf(v.z), fabsf(v.w)));
    #pragma unroll
    for (int s = 1; s < 32; s <<= 1) m = fmaxf(m, __shfl_xor(m, s));
    float sraw = fmaxf(m, 1e-30f);
    float inv = 32767.f / sraw;
    float sv = sraw * (1.f / 32767.f);
    int a0 = (int)rintf(fminf(fmaxf(v.x * inv, -32767.f), 32767.f));
    int a1 = (int)rintf(fminf(fmaxf(v.y * inv, -32767.f), 32767.f));
    int a2 = (int)rintf(fminf(fmaxf(v.z * inv, -32767.f), 32767.f));
    int a3 = (int)rintf(fminf(fmaxf(v.w * inv, -32767.f), 32767.f));
    u32x2 p = {(unsigned)(a0 & 0xffff) | ((unsigned)a1 << 16),
               (unsigned)(a2 & 0xffff) | ((unsigned)a3 << 16)};
    __builtin_nontemporal_store(p, &xq[(size_t)node * 32 + l32]);
    if (l32 == 0) Sn[node] = sv * norm[node];
}

// --------------------------- 128-wide SpMM hops ----------------------------
// int16 gather: row = 32 x u32x2 (8B/lane, half-wave/row). 8 edges in flight
// per iter (4 per half-wave), interleaved form (measured-best).

template <int EPI>  // 0: int16 quant out + S [k1]; 1: Hi/Lo bf16 split out [k2]
__global__ void __launch_bounds__(256) spmm128_q(const u32x2* __restrict__ hq,
                                                 const float* __restrict__ esc,
                                                 const int* __restrict__ rp,
                                                 const int* __restrict__ col,
                                                 const float* __restrict__ norm,
                                                 u32x2* __restrict__ outq,
                                                 float* __restrict__ So,
                                                 u32x2* __restrict__ Hi,
                                                 u32x2* __restrict__ Lo,
                                                 int n) {
    int wid = (blockIdx.x * blockDim.x + threadIdx.x) >> 6;
    if (wid >= n) return;
    int lane = threadIdx.x & 63, half = lane >> 5, l32 = lane & 31;
    int beg = rp[wid], end = rp[wid + 1];
    f32x4 acc = {0.f, 0.f, 0.f, 0.f};
    if (beg < end) {
        int last = end - 1;
        for (int e = beg; e < end; e += 8) {
            int i0 = e + half, i1 = e + 2 + half, i2 = e + 4 + half, i3 = e + 6 + half;
            int i0c = i0 < end ? i0 : last;
            int i1c = i1 < end ? i1 : last;
            int i2c = i2 < end ? i2 : last;
            int i3c = i3 < end ? i3 : last;
            int u0 = col[i0c], u1 = col[i1c], u2 = col[i2c], u3 = col[i3c];
            float s0 = i0 < end ? esc[u0] : 0.f;
            float s1 = i1 < end ? esc[u1] : 0.f;
            float s2 = i2 < end ? esc[u2] : 0.f;
            float s3 = i3 < end ? esc[u3] : 0.f;
            u32x2 q0 = hq[(size_t)u0 * 32 + l32];
            u32x2 q1 = hq[(size_t)u1 * 32 + l32];
            u32x2 q2 = hq[(size_t)u2 * 32 + l32];
            u32x2 q3 = hq[(size_t)u3 * 32 + l32];
            acc.x += (float)(short)(q0.x) * s0;
            acc.y += (float)((int)q0.x >> 16) * s0;
            acc.z += (float)(short)(q0.y) * s0;
            acc.w += (float)((int)q0.y >> 16) * s0;
            acc.x += (float)(short)(q1.x) * s1;
            acc.y += (float)((int)q1.x >> 16) * s1;
            acc.z += (float)(short)(q1.y) * s1;
            acc.w += (float)((int)q1.y >> 16) * s1;
            acc.x += (float)(short)(q2.x) * s2;
            acc.y += (float)((int)q2.x >> 16) * s2;
            acc.z += (float)(short)(q2.y) * s2;
            acc.w += (float)((int)q2.y >> 16) * s2;
            acc.x += (float)(short)(q3.x) * s3;
            acc.y += (float)((int)q3.x >> 16) * s3;
            acc.z += (float)(short)(q3.y) * s3;
            acc.w += (float)((int)q3.y >> 16) * s3;
        }
    }
    acc.x += __shfl_xor(acc.x, 32);
    acc.y += __shfl_xor(acc.y, 32);
    acc.z += __shfl_xor(acc.z, 32);
    acc.w += __shfl_xor(acc.w, 32);
    float nv = norm[wid];
    if (EPI == 0) {
        float f = nv * nv;
        acc.x *= f; acc.y *= f; acc.z *= f; acc.w *= f;
        float m = fmaxf(fmaxf(fabsf(acc.x), fabsf(acc.y)), fmaxf(fabsf(acc.z), fabsf(acc.w)));
        #pragma unroll
        for (int s = 1; s < 64; s <<= 1) m = fmaxf(m, __shfl_xor(m, s));
        float sraw = fmaxf(m, 1e-30f);
        float inv = 32767.f / sraw;
        float sv = sraw * (1.f / 32767.f);
        if (half == 0) {
            int a0 = (int)rintf(fminf(fmaxf(acc.x * inv, -32767.f), 32767.f));
            int a1 = (int)rintf(fminf(fmaxf(acc.y * inv, -32767.f), 32767.f));
            int a2 = (int)rintf(fminf(fmaxf(acc.z * inv, -32767.f), 32767.f));
            int a3 = (int)rintf(fminf(fmaxf(acc.w * inv, -32767.f), 32767.f));
            u32x2 p = {(unsigned)(a0 & 0xffff) | ((unsigned)a1 << 16),
                       (unsigned)(a2 & 0xffff) | ((unsigned)a3 << 16)};
            __builtin_nontemporal_store(p, &outq[(size_t)wid * 32 + l32]);
        }
        if (lane == 0) So[wid] = sv;
    } else {
        if (half == 0) {
            float v0 = acc.x * nv, v1 = acc.y * nv, v2 = acc.z * nv, v3 = acc.w * nv;
            unsigned short h0 = f2bf(v0), h1 = f2bf(v1), h2 = f2bf(v2), h3 = f2bf(v3);
            unsigned short l0 = f2bf(v0 - bf2f(h0)), l1 = f2bf(v1 - bf2f(h1));
            unsigned short l2 = f2bf(v2 - bf2f(h2)), l3 = f2bf(v3 - bf2f(h3));
            u32x2 hp = {(unsigned int)h0 | ((unsigned int)h1 << 16),
                        (unsigned int)h2 | ((unsigned int)h3 << 16)};
            u32x2 lp = {(unsigned int)l0 | ((unsigned int)l1 << 16),
                        (unsigned int)l2 | ((unsigned int)l3 << 16)};
            __builtin_nontemporal_store(hp, &Hi[(size_t)wid * 32 + l32]);
            __builtin_nontemporal_store(lp, &Lo[(size_t)wid * 32 + l32]);
        }
    }
}

// ---------------------------- 40-wide SpMM hops ----------------------------
// int16 rows: 40 int16 = 10 x u32x2 per row. 6 edge-slots x 10 lanes,
// 18 edges in flight.

template <int EPI>  // 0: hop1 (esc=Sn3, f=nv^2, int16 out + S4); 1: hop2 (esc=S4, f=nv, f32 out + b3)
__global__ void __launch_bounds__(256) spmm40_q(const u32x2* __restrict__ hq,
                                                const float* __restrict__ esc,
                                                const int* __restrict__ rp,
                                                const int* __restrict__ col,
                                                const float* __restrict__ norm,
                                                u32x2* __restrict__ outq,
                                                float* __restrict__ So,
                                                f32x4* __restrict__ outf,
                                                const float* __restrict__ b3,
                                                int n) {
    int wid = (blockIdx.x * blockDim.x + threadIdx.x) >> 6;
    if (wid >= n) return;
    int lane = threadIdx.x & 63;
    int slot = lane / 10;      // 0..5 active; lanes 60-63 idle
    int t = lane % 10;
    bool active = slot < 6;
    int beg = rp[wid], end = rp[wid + 1];
    f32x4 acc = {0.f, 0.f, 0.f, 0.f};
    if (beg < end) {
        int last = end - 1;
        for (int base = beg; base < end; base += 18) {
            float s[3];
            u32x2 q[3];
            #pragma unroll
            for (int k = 0; k < 3; ++k) {
                int i = base + 6 * k + slot;
                int ic = (active && i < end) ? i : last;
                int u = col[ic];
                s[k] = (active && i < end) ? esc[u] : 0.f;
                q[k] = hq[(size_t)u * 10 + t];
            }
            #pragma unroll
            for (int k = 0; k < 3; ++k) {
                acc.x += (float)(short)(q[k].x) * s[k];
                acc.y += (float)((int)q[k].x >> 16) * s[k];
                acc.z += (float)(short)(q[k].y) * s[k];
                acc.w += (float)((int)q[k].y >> 16) * s[k];
            }
        }
    }
    f32x4 tot = acc;
    #pragma unroll
    for (int k = 1; k < 6; ++k) {
        int srcl = t + ((slot + k) % 6) * 10;
        tot.x += __shfl(acc.x, srcl);
        tot.y += __shfl(acc.y, srcl);
        tot.z += __shfl(acc.z, srcl);
        tot.w += __shfl(acc.w, srcl);
    }
    float nv = norm[wid];
    if (EPI == 0) {
        float f = nv * nv;
        f32x4 v = {tot.x * f, tot.y * f, tot.z * f, tot.w * f};
        float m = (slot < 6)
                ? fmaxf(fmaxf(fabsf(v.x), fabsf(v.y)), fmaxf(fabsf(v.z), fabsf(v.w)))
                : 0.f;
        #pragma unroll
        for (int s = 1; s < 64; s <<= 1) m = fmaxf(m, __shfl_xor(m, s));
        float sraw = fmaxf(m, 1e-30f);
        float inv = 32767.f / sraw;
        float sv = sraw * (1.f / 32767.f);
        if (slot == 0) {
            int a0 = (int)rintf(fminf(fmaxf(v.x * inv, -32767.f), 32767.f));
            int a1 = (int)rintf(fminf(fmaxf(v.y * inv, -32767.f), 32767.f));
            int a2 = (int)rintf(fminf(fmaxf(v.z * inv, -32767.f), 32767.f));
            int a3 = (int)rintf(fminf(fmaxf(v.w * inv, -32767.f), 32767.f));
            u32x2 p = {(unsigned)(a0 & 0xffff) | ((unsigned)a1 << 16),
                       (unsigned)(a2 & 0xffff) | ((unsigned)a3 << 16)};
            __builtin_nontemporal_store(p, &outq[(size_t)wid * 10 + t]);
        }
        if (lane == 0) So[wid] = sv;
    } else {
        if (slot == 0) {
            f32x4 bv = ((const f32x4*)b3)[t];
            f32x4 o = {tot.x * nv + bv.x, tot.y * nv + bv.y,
                       tot.z * nv + bv.z, tot.w * nv + bv.w};
            __builtin_nontemporal_store(o, &outf[(size_t)wid * 10 + t]);
        }
    }
}

// ------------------------- W fragment preparation --------------------------

__device__ __forceinline__ void wprep_one(const float* __restrict__ W,
                                          short* __restrict__ Wh,
                                          short* __restrict__ Wl,
                                          int ncols, int CF, int i) {
    int j = i & 7;
    int lane = (i >> 3) & 63;
    int f = i >> 9;
    int cf = f % CF, ks = f / CF;
    int k = ks * 32 + 8 * (lane >> 4) + j;
    int c = cf * 16 + (lane & 15);
    float v = (c < ncols) ? W[k * ncols + c] : 0.f;
    unsigned short h = f2bf(v);
    unsigned short l = f2bf(v - bf2f(h));
    Wh[i] = (short)h;
    Wl[i] = (short)l;
}

__global__ void __launch_bounds__(256) wprep_all(const float* __restrict__ W1,
                                                 const float* __restrict__ W2,
                                                 const float* __restrict__ W3,
                                                 short* __restrict__ W1h, short* __restrict__ W1l,
                                                 short* __restrict__ W2h, short* __restrict__ W2l,
                                                 short* __restrict__ W3h, short* __restrict__ W3l) {
    int i = blockIdx.x * blockDim.x + threadIdx.x;
    if (i < 16384) wprep_one(W1, W1h, W1l, 128, 8, i);
    else if (i < 32768) wprep_one(W2, W2h, W2l, 128, 8, i - 16384);
    else if (i < 38912) wprep_one(W3, W3h, W3l, 40, 3, i - 32768);
}

// ------------------------- split-bf16 MFMA GEMMs ---------------------------

__global__ void __launch_bounds__(256) gemm_mfma128(const unsigned short* __restrict__ Ahi,
                                                    const unsigned short* __restrict__ Alo,
                                                    const short8v* __restrict__ Wh,
                                                    const short8v* __restrict__ Wl,
                                                    const float* __restrict__ bias,
                                                    const float* __restrict__ norm,
                                                    unsigned short* __restrict__ Cq,
                                                    float* __restrict__ So,
                                                    float* __restrict__ Sno,
                                                    int n) {
    int lane = threadIdx.x & 63;
    int wid = threadIdx.x >> 6;
    int r0 = blockIdx.x * 64 + wid * 16;
    if (r0 >= n) return;
    int arow = r0 + (lane & 15);
    if (arow > n - 1) arow = n - 1;
    int kbase = 8 * (lane >> 4);
    f32x4 acc[8];
    #pragma unroll
    for (int i = 0; i < 8; ++i) acc[i] = (f32x4){0.f, 0.f, 0.f, 0.f};
    #pragma unroll
    for (int ks = 0; ks < 4; ++ks) {
        short8v ah = *(const short8v*)(Ahi + (size_t)arow * 128 + ks * 32 + kbase);
        short8v al = *(const short8v*)(Alo + (size_t)arow * 128 + ks * 32 + kbase);
        #pragma unroll
        for (int cf = 0; cf < 8; ++cf) {
            short8v bh = Wh[(ks * 8 + cf) * 64 + lane];
            short8v bl = Wl[(ks * 8 + cf) * 64 + lane];
            acc[cf] = __builtin_amdgcn_mfma_f32_16x16x32_bf16(ah, bh, acc[cf], 0, 0, 0);
            acc[cf] = __builtin_amdgcn_mfma_f32_16x16x32_bf16(al, bh, acc[cf], 0, 0, 0);
            acc[cf] = __builtin_amdgcn_mfma_f32_16x16x32_bf16(ah, bl, acc[cf], 0, 0, 0);
        }
    }
    int rbase = r0 + (lane >> 4) * 4;
    int c0 = lane & 15;
    float bc[8];
    #pragma unroll
    for (int cf = 0; cf < 8; ++cf) bc[cf] = bias[cf * 16 + c0];

    float mq[4] = {0.f, 0.f, 0.f, 0.f};
    #pragma unroll
    for (int cf = 0; cf < 8; ++cf) {
        #pragma unroll
        for (int q = 0; q < 4; ++q)
            mq[q] = fmaxf(mq[q], fmaxf(acc[cf][q] + bc[cf], 0.f));
    }
    #pragma unroll
    for (int s = 1; s < 16; s <<= 1) {
        #pragma unroll
        for (int q = 0; q < 4; ++q) mq[q] = fmaxf(mq[q], __shfl_xor(mq[q], s));
    }
    float invq[4], svq[4];
    #pragma unroll
    for (int q = 0; q < 4; ++q) {
        float sraw = fmaxf(mq[q], 1e-30f);
        invq[q] = 32767.f / sraw;
        svq[q] = sraw * (1.f / 32767.f);
    }
    #pragma unroll
    for (int cf = 0; cf < 8; ++cf) {
        int colc = cf * 16 + c0;
        #pragma unroll
        for (int q = 0; q < 4; ++q) {
            int row = rbase + q;
            if (row >= n) continue;
            float v = fmaxf(acc[cf][q] + bc[cf], 0.f);
            int qi = (int)rintf(fminf(v * invq[q], 32767.f));  // v >= 0
            Cq[(size_t)row * 128 + colc] = (unsigned short)qi;
        }
    }
    if (c0 == 0) {
        #pragma unroll
        for (int q = 0; q < 4; ++q) {
            int row = rbase + q;
            if (row < n) { So[row] = svq[q]; Sno[row] = svq[q] * norm[row]; }
        }
    }
}

// 128->40: A from int16+scale (in-register hi/lo split); out int16 + S3/Sn3.
__global__ void __launch_bounds__(256) gemm_mfma40(const unsigned short* __restrict__ Aq,
                                                   const float* __restrict__ SA,
                                                   const short8v* __restrict__ Wh,
                                                   const short8v* __restrict__ Wl,
                                                   const float* __restrict__ norm,
                                                   unsigned short* __restrict__ Cq,
                                                   float* __restrict__ S3,
                                                   float* __restrict__ Sn3,
                                                   int n) {
    int lane = threadIdx.x & 63;
    int wid = threadIdx.x >> 6;
    int r0 = blockIdx.x * 64 + wid * 16;
    if (r0 >= n) return;
    int arow = r0 + (lane & 15);
    if (arow > n - 1) arow = n - 1;
    int kbase = 8 * (lane >> 4);
    float sA = SA[arow];
    f32x4 acc[3];
    #pragma unroll
    for (int i = 0; i < 3; ++i) acc[i] = (f32x4){0.f, 0.f, 0.f, 0.f};
    #pragma unroll
    for (int ks = 0; ks < 4; ++ks) {
        short8v qv = *(const short8v*)(Aq + (size_t)arow * 128 + ks * 32 + kbase);
        short8v ah, al;
        #pragma unroll
        for (int j = 0; j < 8; ++j) {
            float v = (float)qv[j] * sA;
            unsigned int uv = __builtin_bit_cast(unsigned int, v);
            unsigned short hi = (unsigned short)(uv >> 16);      // trunc bf16
            float r = v - bf2f(hi);
            ah[j] = (short)hi;
            al[j] = (short)f2bf(r);
        }
        #pragma unroll
        for (int cf = 0; cf < 3; ++cf) {
            short8v bh = Wh[(ks * 3 + cf) * 64 + lane];
            short8v bl = Wl[(ks * 3 + cf) * 64 + lane];
            acc[cf] = __builtin_amdgcn_mfma_f32_16x16x32_bf16(ah, bh, acc[cf], 0, 0, 0);
            acc[cf] = __builtin_amdgcn_mfma_f32_16x16x32_bf16(al, bh, acc[cf], 0, 0, 0);
            acc[cf] = __builtin_amdgcn_mfma_f32_16x16x32_bf16(ah, bl, acc[cf], 0, 0, 0);
        }
    }
    int rbase = r0 + (lane >> 4) * 4;
    int c0 = lane & 15;
    float mq[4] = {0.f, 0.f, 0.f, 0.f};
    #pragma unroll
    for (int cf = 0; cf < 3; ++cf) {
        int colc = cf * 16 + c0;
        if (colc < 40) {
            #pragma unroll
            for (int q = 0; q < 4; ++q) mq[q] = fmaxf(mq[q], fabsf(acc[cf][q]));
        }
    }
    #pragma unroll
    for (int s = 1; s < 16; s <<= 1) {
        #pragma unroll
        for (int q = 0; q < 4; ++q) mq[q] = fmaxf(mq[q], __shfl_xor(mq[q], s));
    }
    float invq[4], svq[4];
    #pragma unroll
    for (int q = 0; q < 4; ++q) {
        float sraw = fmaxf(mq[q], 1e-30f);
        invq[q] = 32767.f / sraw;
        svq[q] = sraw * (1.f / 32767.f);
    }
    #pragma unroll
    for (int cf = 0; cf < 3; ++cf) {
        int colc = cf * 16 + c0;
        if (colc >= 40) continue;
        #pragma unroll
        for (int q = 0; q < 4; ++q) {
            int row = rbase + q;
            if (row >= n) continue;
            float v = acc[cf][q];
            int qi = (int)rintf(fminf(fmaxf(v * invq[q], -32767.f), 32767.f));
            Cq[(size_t)row * 40 + colc] = (unsigned short)qi;
        }
    }
    if (c0 == 0) {
        #pragma unroll
        for (int q = 0; q < 4; ++q) {
            int row = rbase + q;
            if (row < n) { S3[row] = svq[q]; Sn3[row] = svq[q] * norm[row]; }
        }
    }
}

// --------------------------------- launch ----------------------------------

extern "C" void kernel_launch(void* const* d_in, const int* in_sizes, int n_in,
                              void* d_out, int out_size, void* d_ws, size_t ws_size,
                              hipStream_t stream) {
    const float* features = (const float*)d_in[0];
    const int*   src      = (const int*)d_in[1];
    const int*   dst      = (const int*)d_in[2];
    const float* W1 = (const float*)d_in[3];
    const float* b1 = (const float*)d_in[4];
    const float* W2 = (const float*)d_in[5];
    const float* b2 = (const float*)d_in[6];
    const float* W3 = (const float*)d_in[7];
    const float* b3 = (const float*)d_in[8];
    float* out = (float*)d_out;

    const int N = in_sizes[0] / 128;
    const int E = in_sizes[1];

    char* ws = (char*)d_ws;
    size_t off = 0;
    auto alloc = [&](size_t bytes) -> void* {
        void* p = ws + off;
        off += (bytes + 511) & ~(size_t)511;
        return p;
    };
    u32x2* QA = (u32x2*)alloc((size_t)N * 32 * sizeof(u32x2));
    u32x2* QB = (u32x2*)alloc((size_t)N * 32 * sizeof(u32x2));
    unsigned short* Hi = (unsigned short*)alloc((size_t)N * 128 * sizeof(unsigned short));
    unsigned short* Lo = (unsigned short*)alloc((size_t)N * 128 * sizeof(unsigned short));
    float* Snx = (float*)alloc((size_t)N * sizeof(float));
    float* Sk  = (float*)alloc((size_t)N * sizeof(float));
    float* Sg  = (float*)alloc((size_t)N * sizeof(float));
    float* Sng = (float*)alloc((size_t)N * sizeof(float));
    float* S3  = (float*)alloc((size_t)N * sizeof(float));
    float* Sn3 = (float*)alloc((size_t)N * sizeof(float));
    float* S4  = (float*)alloc((size_t)N * sizeof(float));
    int*   col    = (int*)alloc((size_t)E * sizeof(int));
    int*   deg    = (int*)alloc((size_t)N * sizeof(int));
    int*   rowptr = (int*)alloc((size_t)(N + 1) * sizeof(int));
    float* norm   = (float*)alloc((size_t)N * sizeof(float));
    int*   bsum   = (int*)alloc((size_t)(SBLK + 2) * sizeof(int));
    short* W1h = (short*)alloc(16384 * sizeof(short));
    short* W1l = (short*)alloc(16384 * sizeof(short));
    short* W2h = (short*)alloc(16384 * sizeof(short));
    short* W2l = (short*)alloc(16384 * sizeof(short));
    short* W3h = (short*)alloc(6144 * sizeof(short));
    short* W3l = (short*)alloc(6144 * sizeof(short));
    int*   rank = (int*)Hi;
    u32x2* G1 = (u32x2*)QB;   // QB dead after k2 of layer 2
    u32x2* G2 = (u32x2*)Hi;   // Hi dead after gemm40 consumed... (via QA path)

    const int seg = (N + SBLK - 1) / SBLK;
    const int eblocks = (E + 255) / 256;

    // --- CSR build ---
    hipMemsetAsync(deg, 0, (size_t)N * sizeof(int), stream);
    deg_rank_kernel<<<eblocks, 256, 0, stream>>>(dst, deg, rank, E);
    scanA_kernel<<<SBLK, 256, 0, stream>>>(deg, rowptr, bsum, norm, N, seg);
    scanC_kernel<<<SBLK, 256, 0, stream>>>(rowptr, bsum, N, seg);
    fill_kernel<<<eblocks, 256, 0, stream>>>(src, dst, rowptr, rank, col, E);

    // --- W fragment prep + input quantization ---
    wprep_all<<<(38912 + 255) / 256, 256, 0, stream>>>(W1, W2, W3, W1h, W1l, W2h, W2l, W3h, W3l);
    {
        int waves2 = (N + 1) / 2;
        int xblocks = (waves2 * 64 + 255) / 256;
        xquant_kernel<<<xblocks, 256, 0, stream>>>((const float4*)features, norm, QA, Snx, N);
    }

    const int spmm_blocks = (N * 64 + 255) / 256;  // one wave per node
    const int gemm_blocks = (N + 63) / 64;

    // layer 1
    spmm128_q<0><<<spmm_blocks, 256, 0, stream>>>(QA, Snx, rowptr, col, norm,
                                                  QB, Sk, nullptr, nullptr, N);
    spmm128_q<1><<<spmm_blocks, 256, 0, stream>>>(QB, Sk, rowptr, col, norm,
                                                  nullptr, nullptr, (u32x2*)Hi, (u32x2*)Lo, N);
    gemm_mfma128<<<gemm_blocks, 256, 0, stream>>>(Hi, Lo, (const short8v*)W1h, (const short8v*)W1l,
                                                  b1, norm, (unsigned short*)QA, Sg, Sng, N);

    // layer 2
    spmm128_q<0><<<spmm_blocks, 256, 0, stream>>>(QA, Sng, rowptr, col, norm,
                                                  QB, Sk, nullptr, nullptr, N);
    spmm128_q<1><<<spmm_blocks, 256, 0, stream>>>(QB, Sk, rowptr, col, norm,
                                                  nullptr, nullptr, (u32x2*)Hi, (u32x2*)Lo, N);
    gemm_mfma128<<<gemm_blocks, 256, 0, stream>>>(Hi, Lo, (const short8v*)W2h, (const short8v*)W2l,
                                                  b2, norm, (unsigned short*)QA, Sg, Sng, N);

    // layer 3 (reordered): project 128->40 (int16 in/out), then 2 hops at 40-wide
    gemm_mfma40<<<gemm_blocks, 256, 0, stream>>>((const unsigned short*)QA, Sg,
                                                 (const short8v*)W3h, (const short8v*)W3l,
                                                 norm, (unsigned short*)G1, S3, Sn3, N);
    spmm40_q<0><<<spmm_blocks, 256, 0, stream>>>(G1, Sn3, rowptr, col, norm,
                                                 G2, S4, nullptr, nullptr, N);
    spmm40_q<1><<<spmm_blocks, 256, 0, stream>>>(G2, S4, rowptr, col, norm,
                                                 nullptr, nullptr, (f32x4*)out, b3, N);
}

// Round 10
// 627.205 us; speedup vs baseline: 1.1011x; 1.0141x over previous
//
#include <hip/hip_runtime.h>
#include <hip/hip_bf16.h>

// ---------------------------------------------------------------------------
// DeepSGC on MI355X:
//   - CSR build per call: rank-recording deg pass, 2-kernel scan, atomic-free fill
//   - ALL hop traffic int16 row-quantized (128-wide: 256B/row; 40-wide: 80B/row)
//     with per-row scale S (dequant) and Sn = S*norm (fuses the norm gather-scale)
//   - hop pairs folded: k1: z = N^2 A (Sn gather); k2: y = N A z (S gather)
//   - 128-wide SpMM: unroll 8 interleaved + 1-iter col/esc software prefetch
//   - GEMMs: 3x bf16 MFMA split-precision, int16 A dequantized in-register
//   - layer-3 reorder: project 128->40 first, then 2 hops at 40-wide
// ---------------------------------------------------------------------------

typedef __attribute__((ext_vector_type(8))) short short8v;   // 8 x bf16
typedef __attribute__((ext_vector_type(4))) float f32x4;
typedef __attribute__((ext_vector_type(2))) unsigned int u32x2;

#define SBLK 128  // scan segments

__device__ __forceinline__ unsigned short f2bf(float x) {
    unsigned int u = __builtin_bit_cast(unsigned int, x);
    unsigned int r = u + 0x7fffu + ((u >> 16) & 1u);   // RNE
    return (unsigned short)(r >> 16);
}
__device__ __forceinline__ float bf2f(unsigned short h) {
    unsigned int u = ((unsigned int)h) << 16;
    return __builtin_bit_cast(float, u);
}

// ------------------------------- CSR build --------------------------------

__global__ void __launch_bounds__(256) deg_rank_kernel(const int* __restrict__ dst,
                                                       int* __restrict__ deg,
                                                       int* __restrict__ rank, int E) {
    int e = blockIdx.x * blockDim.x + threadIdx.x;
    if (e < E) rank[e] = atomicAdd(&deg[dst[e]], 1);
}

__global__ void __launch_bounds__(256) scanA_kernel(const int* __restrict__ deg,
                                                    int* __restrict__ rowptr,
                                                    int* __restrict__ bsum,
                                                    float* __restrict__ norm,
                                                    int n, int seg) {
    __shared__ int ws[4];
    __shared__ int carry;
    int b = blockIdx.x;
    int start = b * seg;
    int finish = start + seg; if (finish > n) finish = n;
    int t = threadIdx.x, lane = t & 63, w = t >> 6;
    if (t == 0) carry = 0;
    __syncthreads();
    for (int base = start; base < finish; base += 256) {
        int i = base + t;
        int v = 0;
        if (i < finish) {
            v = deg[i];
            norm[i] = rsqrtf((float)(v < 1 ? 1 : v));
        }
        int x = v;
        #pragma unroll
        for (int off = 1; off < 64; off <<= 1) {
            int y = __shfl_up(x, off, 64);
            if (lane >= off) x += y;
        }
        if (lane == 63) ws[w] = x;
        __syncthreads();
        int woff = 0;
        #pragma unroll
        for (int k = 0; k < 4; ++k) if (k < w) woff += ws[k];
        if (i < finish) rowptr[i] = carry + woff + x - v;
        int tot = ws[0] + ws[1] + ws[2] + ws[3];
        __syncthreads();
        if (t == 0) carry += tot;
        __syncthreads();
    }
    if (t == 0) bsum[b] = carry;
}

__global__ void __launch_bounds__(256) scanC_kernel(int* __restrict__ rowptr,
                                                    const int* __restrict__ bsum,
                                                    int n, int seg) {
    __shared__ int tmp[SBLK + 1];
    int b = blockIdx.x, t = threadIdx.x;
    if (t < SBLK) tmp[t] = bsum[t];
    __syncthreads();
    if (t == 0) {
        int s = 0;
        #pragma unroll 4
        for (int i = 0; i < SBLK; ++i) { int v = tmp[i]; tmp[i] = s; s += v; }
        tmp[SBLK] = s;
    }
    __syncthreads();
    int add = tmp[b];
    int start = b * seg;
    int finish = start + seg; if (finish > n) finish = n;
    for (int i = start + t; i < finish; i += 256) rowptr[i] += add;
    if (b == 0 && t == 0) rowptr[n] = tmp[SBLK];
}

__global__ void __launch_bounds__(256) fill_kernel(const int* __restrict__ src,
                                                   const int* __restrict__ dst,
                                                   const int* __restrict__ rowptr,
                                                   const int* __restrict__ rank,
                                                   int* __restrict__ col, int E) {
    int e = blockIdx.x * blockDim.x + threadIdx.x;
    if (e < E) col[rowptr[dst[e]] + rank[e]] = src[e];
}

// ------------------------ input row quantization ---------------------------

__global__ void __launch_bounds__(256) xquant_kernel(const float4* __restrict__ x,
                                                     const float* __restrict__ norm,
                                                     u32x2* __restrict__ xq,
                                                     float* __restrict__ Sn,
                                                     int n) {
    int gw = (blockIdx.x * blockDim.x + threadIdx.x) >> 6;
    int lane = threadIdx.x & 63, half = lane >> 5, l32 = lane & 31;
    int node = gw * 2 + half;
    if (node >= n) return;
    float4 v = x[(size_t)node * 32 + l32];
    float m = fmaxf(fmaxf(fabsf(v.x), fabsf(v.y)), fmaxf(fabsf(v.z), fabsf(v.w)));
    #pragma unroll
    for (int s = 1; s < 32; s <<= 1) m = fmaxf(m, __shfl_xor(m, s));
    float sraw = fmaxf(m, 1e-30f);
    float inv = 32767.f / sraw;
    float sv = sraw * (1.f / 32767.f);
    int a0 = (int)rintf(fminf(fmaxf(v.x * inv, -32767.f), 32767.f));
    int a1 = (int)rintf(fminf(fmaxf(v.y * inv, -32767.f), 32767.f));
    int a2 = (int)rintf(fminf(fmaxf(v.z * inv, -32767.f), 32767.f));
    int a3 = (int)rintf(fminf(fmaxf(v.w * inv, -32767.f), 32767.f));
    u32x2 p = {(unsigned)(a0 & 0xffff) | ((unsigned)a1 << 16),
               (unsigned)(a2 & 0xffff) | ((unsigned)a3 << 16)};
    __builtin_nontemporal_store(p, &xq[(size_t)node * 32 + l32]);
    if (l32 == 0) Sn[node] = sv * norm[node];
}

// --------------------------- 128-wide SpMM hops ----------------------------
// int16 gather: row = 32 x u32x2 (8B/lane, half-wave/row). 8 edges in flight
// per iter + next iteration's col/esc prefetched (hides the dependent chain).
// SQ=1: k1, f=nv^2 (esc=Sn of producer). SQ=0: k2, f=nv (esc=S of k1).
// Output: int16 row + per-row scale S.

template <int SQ>
__global__ void __launch_bounds__(256, 8) spmm128_q(const u32x2* __restrict__ hq,
                                                    const float* __restrict__ esc,
                                                    const int* __restrict__ rp,
                                                    const int* __restrict__ col,
                                                    const float* __restrict__ norm,
                                                    u32x2* __restrict__ outq,
                                                    float* __restrict__ So,
                                                    int n) {
    int wid = (blockIdx.x * blockDim.x + threadIdx.x) >> 6;
    if (wid >= n) return;
    int lane = threadIdx.x & 63, half = lane >> 5, l32 = lane & 31;
    int beg = rp[wid], end = rp[wid + 1];
    f32x4 acc = {0.f, 0.f, 0.f, 0.f};
    if (beg < end) {
        int last = end - 1;
        int u0, u1, u2, u3;
        float s0, s1, s2, s3;
        {
            int i0 = beg + half, i1 = beg + 2 + half, i2 = beg + 4 + half, i3 = beg + 6 + half;
            int i0c = i0 < end ? i0 : last;
            int i1c = i1 < end ? i1 : last;
            int i2c = i2 < end ? i2 : last;
            int i3c = i3 < end ? i3 : last;
            u0 = col[i0c]; u1 = col[i1c]; u2 = col[i2c]; u3 = col[i3c];
            s0 = i0 < end ? esc[u0] : 0.f;
            s1 = i1 < end ? esc[u1] : 0.f;
            s2 = i2 < end ? esc[u2] : 0.f;
            s3 = i3 < end ? esc[u3] : 0.f;
        }
        for (int e = beg; e < end; e += 8) {
            // issue current gathers
            u32x2 q0 = hq[(size_t)u0 * 32 + l32];
            u32x2 q1 = hq[(size_t)u1 * 32 + l32];
            u32x2 q2 = hq[(size_t)u2 * 32 + l32];
            u32x2 q3 = hq[(size_t)u3 * 32 + l32];
            // prefetch next iteration's col + esc (under the gathers)
            int en = e + 8;
            int j0 = en + half, j1 = en + 2 + half, j2 = en + 4 + half, j3 = en + 6 + half;
            int j0c = j0 < end ? j0 : last;
            int j1c = j1 < end ? j1 : last;
            int j2c = j2 < end ? j2 : last;
            int j3c = j3 < end ? j3 : last;
            int nu0 = col[j0c], nu1 = col[j1c], nu2 = col[j2c], nu3 = col[j3c];
            float ns0 = j0 < end ? esc[nu0] : 0.f;
            float ns1 = j1 < end ? esc[nu1] : 0.f;
            float ns2 = j2 < end ? esc[nu2] : 0.f;
            float ns3 = j3 < end ? esc[nu3] : 0.f;
            // accumulate current
            acc.x += (float)(short)(q0.x) * s0;
            acc.y += (float)((int)q0.x >> 16) * s0;
            acc.z += (float)(short)(q0.y) * s0;
            acc.w += (float)((int)q0.y >> 16) * s0;
            acc.x += (float)(short)(q1.x) * s1;
            acc.y += (float)((int)q1.x >> 16) * s1;
            acc.z += (float)(short)(q1.y) * s1;
            acc.w += (float)((int)q1.y >> 16) * s1;
            acc.x += (float)(short)(q2.x) * s2;
            acc.y += (float)((int)q2.x >> 16) * s2;
            acc.z += (float)(short)(q2.y) * s2;
            acc.w += (float)((int)q2.y >> 16) * s2;
            acc.x += (float)(short)(q3.x) * s3;
            acc.y += (float)((int)q3.x >> 16) * s3;
            acc.z += (float)(short)(q3.y) * s3;
            acc.w += (float)((int)q3.y >> 16) * s3;
            u0 = nu0; u1 = nu1; u2 = nu2; u3 = nu3;
            s0 = ns0; s1 = ns1; s2 = ns2; s3 = ns3;
        }
    }
    acc.x += __shfl_xor(acc.x, 32);
    acc.y += __shfl_xor(acc.y, 32);
    acc.z += __shfl_xor(acc.z, 32);
    acc.w += __shfl_xor(acc.w, 32);
    float nv = norm[wid];
    float f = SQ ? nv * nv : nv;
    acc.x *= f; acc.y *= f; acc.z *= f; acc.w *= f;
    float m = fmaxf(fmaxf(fabsf(acc.x), fabsf(acc.y)), fmaxf(fabsf(acc.z), fabsf(acc.w)));
    #pragma unroll
    for (int s = 1; s < 64; s <<= 1) m = fmaxf(m, __shfl_xor(m, s));
    float sraw = fmaxf(m, 1e-30f);
    float inv = 32767.f / sraw;
    float sv = sraw * (1.f / 32767.f);
    if (half == 0) {
        int a0 = (int)rintf(fminf(fmaxf(acc.x * inv, -32767.f), 32767.f));
        int a1 = (int)rintf(fminf(fmaxf(acc.y * inv, -32767.f), 32767.f));
        int a2 = (int)rintf(fminf(fmaxf(acc.z * inv, -32767.f), 32767.f));
        int a3 = (int)rintf(fminf(fmaxf(acc.w * inv, -32767.f), 32767.f));
        u32x2 p = {(unsigned)(a0 & 0xffff) | ((unsigned)a1 << 16),
                   (unsigned)(a2 & 0xffff) | ((unsigned)a3 << 16)};
        __builtin_nontemporal_store(p, &outq[(size_t)wid * 32 + l32]);
    }
    if (lane == 0) So[wid] = sv;
}

// ---------------------------- 40-wide SpMM hops ----------------------------
// int16 rows: 40 int16 = 10 x u32x2 per row. 6 edge-slots x 10 lanes,
// 18 edges in flight.

template <int EPI>  // 0: hop1 (esc=Sn3, f=nv^2, int16 out + S4); 1: hop2 (esc=S4, f=nv, f32 out + b3)
__global__ void __launch_bounds__(256, 8) spmm40_q(const u32x2* __restrict__ hq,
                                                   const float* __restrict__ esc,
                                                   const int* __restrict__ rp,
                                                   const int* __restrict__ col,
                                                   const float* __restrict__ norm,
                                                   u32x2* __restrict__ outq,
                                                   float* __restrict__ So,
                                                   f32x4* __restrict__ outf,
                                                   const float* __restrict__ b3,
                                                   int n) {
    int wid = (blockIdx.x * blockDim.x + threadIdx.x) >> 6;
    if (wid >= n) return;
    int lane = threadIdx.x & 63;
    int slot = lane / 10;      // 0..5 active; lanes 60-63 idle
    int t = lane % 10;
    bool active = slot < 6;
    int beg = rp[wid], end = rp[wid + 1];
    f32x4 acc = {0.f, 0.f, 0.f, 0.f};
    if (beg < end) {
        int last = end - 1;
        for (int base = beg; base < end; base += 18) {
            float s[3];
            u32x2 q[3];
            #pragma unroll
            for (int k = 0; k < 3; ++k) {
                int i = base + 6 * k + slot;
                int ic = (active && i < end) ? i : last;
                int u = col[ic];
                s[k] = (active && i < end) ? esc[u] : 0.f;
                q[k] = hq[(size_t)u * 10 + t];
            }
            #pragma unroll
            for (int k = 0; k < 3; ++k) {
                acc.x += (float)(short)(q[k].x) * s[k];
                acc.y += (float)((int)q[k].x >> 16) * s[k];
                acc.z += (float)(short)(q[k].y) * s[k];
                acc.w += (float)((int)q[k].y >> 16) * s[k];
            }
        }
    }
    f32x4 tot = acc;
    #pragma unroll
    for (int k = 1; k < 6; ++k) {
        int srcl = t + ((slot + k) % 6) * 10;
        tot.x += __shfl(acc.x, srcl);
        tot.y += __shfl(acc.y, srcl);
        tot.z += __shfl(acc.z, srcl);
        tot.w += __shfl(acc.w, srcl);
    }
    float nv = norm[wid];
    if (EPI == 0) {
        float f = nv * nv;
        f32x4 v = {tot.x * f, tot.y * f, tot.z * f, tot.w * f};
        float m = (slot < 6)
                ? fmaxf(fmaxf(fabsf(v.x), fabsf(v.y)), fmaxf(fabsf(v.z), fabsf(v.w)))
                : 0.f;
        #pragma unroll
        for (int s = 1; s < 64; s <<= 1) m = fmaxf(m, __shfl_xor(m, s));
        float sraw = fmaxf(m, 1e-30f);
        float inv = 32767.f / sraw;
        float sv = sraw * (1.f / 32767.f);
        if (slot == 0) {
            int a0 = (int)rintf(fminf(fmaxf(v.x * inv, -32767.f), 32767.f));
            int a1 = (int)rintf(fminf(fmaxf(v.y * inv, -32767.f), 32767.f));
            int a2 = (int)rintf(fminf(fmaxf(v.z * inv, -32767.f), 32767.f));
            int a3 = (int)rintf(fminf(fmaxf(v.w * inv, -32767.f), 32767.f));
            u32x2 p = {(unsigned)(a0 & 0xffff) | ((unsigned)a1 << 16),
                       (unsigned)(a2 & 0xffff) | ((unsigned)a3 << 16)};
            __builtin_nontemporal_store(p, &outq[(size_t)wid * 10 + t]);
        }
        if (lane == 0) So[wid] = sv;
    } else {
        if (slot == 0) {
            f32x4 bv = ((const f32x4*)b3)[t];
            f32x4 o = {tot.x * nv + bv.x, tot.y * nv + bv.y,
                       tot.z * nv + bv.z, tot.w * nv + bv.w};
            __builtin_nontemporal_store(o, &outf[(size_t)wid * 10 + t]);
        }
    }
}

// ------------------------- W fragment preparation --------------------------

__device__ __forceinline__ void wprep_one(const float* __restrict__ W,
                                          short* __restrict__ Wh,
                                          short* __restrict__ Wl,
                                          int ncols, int CF, int i) {
    int j = i & 7;
    int lane = (i >> 3) & 63;
    int f = i >> 9;
    int cf = f % CF, ks = f / CF;
    int k = ks * 32 + 8 * (lane >> 4) + j;
    int c = cf * 16 + (lane & 15);
    float v = (c < ncols) ? W[k * ncols + c] : 0.f;
    unsigned short h = f2bf(v);
    unsigned short l = f2bf(v - bf2f(h));
    Wh[i] = (short)h;
    Wl[i] = (short)l;
}

__global__ void __launch_bounds__(256) wprep_all(const float* __restrict__ W1,
                                                 const float* __restrict__ W2,
                                                 const float* __restrict__ W3,
                                                 short* __restrict__ W1h, short* __restrict__ W1l,
                                                 short* __restrict__ W2h, short* __restrict__ W2l,
                                                 short* __restrict__ W3h, short* __restrict__ W3l) {
    int i = blockIdx.x * blockDim.x + threadIdx.x;
    if (i < 16384) wprep_one(W1, W1h, W1l, 128, 8, i);
    else if (i < 32768) wprep_one(W2, W2h, W2l, 128, 8, i - 16384);
    else if (i < 38912) wprep_one(W3, W3h, W3l, 40, 3, i - 32768);
}

// ------------------------- split-bf16 MFMA GEMMs ---------------------------
// A from int16+scale, dequantized in-register to bf16 hi/lo (exact to ~2^-16).

__global__ void __launch_bounds__(256) gemm_mfma128(const unsigned short* __restrict__ Aq,
                                                    const float* __restrict__ SA,
                                                    const short8v* __restrict__ Wh,
                                                    const short8v* __restrict__ Wl,
                                                    const float* __restrict__ bias,
                                                    const float* __restrict__ norm,
                                                    unsigned short* __restrict__ Cq,
                                                    float* __restrict__ So,
                                                    float* __restrict__ Sno,
                                                    int n) {
    int lane = threadIdx.x & 63;
    int wid = threadIdx.x >> 6;
    int r0 = blockIdx.x * 64 + wid * 16;
    if (r0 >= n) return;
    int arow = r0 + (lane & 15);
    if (arow > n - 1) arow = n - 1;
    int kbase = 8 * (lane >> 4);
    float sA = SA[arow];
    f32x4 acc[8];
    #pragma unroll
    for (int i = 0; i < 8; ++i) acc[i] = (f32x4){0.f, 0.f, 0.f, 0.f};
    #pragma unroll
    for (int ks = 0; ks < 4; ++ks) {
        short8v qv = *(const short8v*)(Aq + (size_t)arow * 128 + ks * 32 + kbase);
        short8v ah, al;
        #pragma unroll
        for (int j = 0; j < 8; ++j) {
            float v = (float)qv[j] * sA;
            unsigned int uv = __builtin_bit_cast(unsigned int, v);
            unsigned short hi = (unsigned short)(uv >> 16);      // trunc bf16
            float r = v - bf2f(hi);
            ah[j] = (short)hi;
            al[j] = (short)f2bf(r);
        }
        #pragma unroll
        for (int cf = 0; cf < 8; ++cf) {
            short8v bh = Wh[(ks * 8 + cf) * 64 + lane];
            short8v bl = Wl[(ks * 8 + cf) * 64 + lane];
            acc[cf] = __builtin_amdgcn_mfma_f32_16x16x32_bf16(ah, bh, acc[cf], 0, 0, 0);
            acc[cf] = __builtin_amdgcn_mfma_f32_16x16x32_bf16(al, bh, acc[cf], 0, 0, 0);
            acc[cf] = __builtin_amdgcn_mfma_f32_16x16x32_bf16(ah, bl, acc[cf], 0, 0, 0);
        }
    }
    int rbase = r0 + (lane >> 4) * 4;
    int c0 = lane & 15;
    float bc[8];
    #pragma unroll
    for (int cf = 0; cf < 8; ++cf) bc[cf] = bias[cf * 16 + c0];

    float mq[4] = {0.f, 0.f, 0.f, 0.f};
    #pragma unroll
    for (int cf = 0; cf < 8; ++cf) {
        #pragma unroll
        for (int q = 0; q < 4; ++q)
            mq[q] = fmaxf(mq[q], fmaxf(acc[cf][q] + bc[cf], 0.f));
    }
    #pragma unroll
    for (int s = 1; s < 16; s <<= 1) {
        #pragma unroll
        for (int q = 0; q < 4; ++q) mq[q] = fmaxf(mq[q], __shfl_xor(mq[q], s));
    }
    float invq[4], svq[4];
    #pragma unroll
    for (int q = 0; q < 4; ++q) {
        float sraw = fmaxf(mq[q], 1e-30f);
        invq[q] = 32767.f / sraw;
        svq[q] = sraw * (1.f / 32767.f);
    }
    #pragma unroll
    for (int cf = 0; cf < 8; ++cf) {
        int colc = cf * 16 + c0;
        #pragma unroll
        for (int q = 0; q < 4; ++q) {
            int row = rbase + q;
            if (row >= n) continue;
            float v = fmaxf(acc[cf][q] + bc[cf], 0.f);
            int qi = (int)rintf(fminf(v * invq[q], 32767.f));  // v >= 0
            Cq[(size_t)row * 128 + colc] = (unsigned short)qi;
        }
    }
    if (c0 == 0) {
        #pragma unroll
        for (int q = 0; q < 4; ++q) {
            int row = rbase + q;
            if (row < n) { So[row] = svq[q]; Sno[row] = svq[q] * norm[row]; }
        }
    }
}

// 128->40: A from int16+scale; out int16 + S3/Sn3.
__global__ void __launch_bounds__(256) gemm_mfma40(const unsigned short* __restrict__ Aq,
                                                   const float* __restrict__ SA,
                                                   const short8v* __restrict__ Wh,
                                                   const short8v* __restrict__ Wl,
                                                   const float* __restrict__ norm,
                                                   unsigned short* __restrict__ Cq,
                                                   float* __restrict__ S3,
                                                   float* __restrict__ Sn3,
                                                   int n) {
    int lane = threadIdx.x & 63;
    int wid = threadIdx.x >> 6;
    int r0 = blockIdx.x * 64 + wid * 16;
    if (r0 >= n) return;
    int arow = r0 + (lane & 15);
    if (arow > n - 1) arow = n - 1;
    int kbase = 8 * (lane >> 4);
    float sA = SA[arow];
    f32x4 acc[3];
    #pragma unroll
    for (int i = 0; i < 3; ++i) acc[i] = (f32x4){0.f, 0.f, 0.f, 0.f};
    #pragma unroll
    for (int ks = 0; ks < 4; ++ks) {
        short8v qv = *(const short8v*)(Aq + (size_t)arow * 128 + ks * 32 + kbase);
        short8v ah, al;
        #pragma unroll
        for (int j = 0; j < 8; ++j) {
            float v = (float)qv[j] * sA;
            unsigned int uv = __builtin_bit_cast(unsigned int, v);
            unsigned short hi = (unsigned short)(uv >> 16);      // trunc bf16
            float r = v - bf2f(hi);
            ah[j] = (short)hi;
            al[j] = (short)f2bf(r);
        }
        #pragma unroll
        for (int cf = 0; cf < 3; ++cf) {
            short8v bh = Wh[(ks * 3 + cf) * 64 + lane];
            short8v bl = Wl[(ks * 3 + cf) * 64 + lane];
            acc[cf] = __builtin_amdgcn_mfma_f32_16x16x32_bf16(ah, bh, acc[cf], 0, 0, 0);
            acc[cf] = __builtin_amdgcn_mfma_f32_16x16x32_bf16(al, bh, acc[cf], 0, 0, 0);
            acc[cf] = __builtin_amdgcn_mfma_f32_16x16x32_bf16(ah, bl, acc[cf], 0, 0, 0);
        }
    }
    int rbase = r0 + (lane >> 4) * 4;
    int c0 = lane & 15;
    float mq[4] = {0.f, 0.f, 0.f, 0.f};
    #pragma unroll
    for (int cf = 0; cf < 3; ++cf) {
        int colc = cf * 16 + c0;
        if (colc < 40) {
            #pragma unroll
            for (int q = 0; q < 4; ++q) mq[q] = fmaxf(mq[q], fabsf(acc[cf][q]));
        }
    }
    #pragma unroll
    for (int s = 1; s < 16; s <<= 1) {
        #pragma unroll
        for (int q = 0; q < 4; ++q) mq[q] = fmaxf(mq[q], __shfl_xor(mq[q], s));
    }
    float invq[4], svq[4];
    #pragma unroll
    for (int q = 0; q < 4; ++q) {
        float sraw = fmaxf(mq[q], 1e-30f);
        invq[q] = 32767.f / sraw;
        svq[q] = sraw * (1.f / 32767.f);
    }
    #pragma unroll
    for (int cf = 0; cf < 3; ++cf) {
        int colc = cf * 16 + c0;
        if (colc >= 40) continue;
        #pragma unroll
        for (int q = 0; q < 4; ++q) {
            int row = rbase + q;
            if (row >= n) continue;
            float v = acc[cf][q];
            int qi = (int)rintf(fminf(fmaxf(v * invq[q], -32767.f), 32767.f));
            Cq[(size_t)row * 40 + colc] = (unsigned short)qi;
        }
    }
    if (c0 == 0) {
        #pragma unroll
        for (int q = 0; q < 4; ++q) {
            int row = rbase + q;
            if (row < n) { S3[row] = svq[q]; Sn3[row] = svq[q] * norm[row]; }
        }
    }
}

// --------------------------------- launch ----------------------------------

extern "C" void kernel_launch(void* const* d_in, const int* in_sizes, int n_in,
                              void* d_out, int out_size, void* d_ws, size_t ws_size,
                              hipStream_t stream) {
    const float* features = (const float*)d_in[0];
    const int*   src      = (const int*)d_in[1];
    const int*   dst      = (const int*)d_in[2];
    const float* W1 = (const float*)d_in[3];
    const float* b1 = (const float*)d_in[4];
    const float* W2 = (const float*)d_in[5];
    const float* b2 = (const float*)d_in[6];
    const float* W3 = (const float*)d_in[7];
    const float* b3 = (const float*)d_in[8];
    float* out = (float*)d_out;

    const int N = in_sizes[0] / 128;
    const int E = in_sizes[1];

    char* ws = (char*)d_ws;
    size_t off = 0;
    auto alloc = [&](size_t bytes) -> void* {
        void* p = ws + off;
        off += (bytes + 511) & ~(size_t)511;
        return p;
    };
    // int16 feature buffers [N][128] (25.6 MB each)
    u32x2* QA = (u32x2*)alloc((size_t)N * 32 * sizeof(u32x2));
    u32x2* QB = (u32x2*)alloc((size_t)N * 32 * sizeof(u32x2));
    u32x2* QC = (u32x2*)alloc((size_t)N * 32 * sizeof(u32x2));
    // scales
    float* Snx = (float*)alloc((size_t)N * sizeof(float));  // producer Sn feeding k1
    float* Sk  = (float*)alloc((size_t)N * sizeof(float));  // k1 output S
    float* Sq2 = (float*)alloc((size_t)N * sizeof(float));  // k2 output S
    float* Sg  = (float*)alloc((size_t)N * sizeof(float));  // gemm128 output S
    float* Sng = (float*)alloc((size_t)N * sizeof(float));  // gemm128 output Sn
    float* S3  = (float*)alloc((size_t)N * sizeof(float));  // g40 output S
    float* Sn3 = (float*)alloc((size_t)N * sizeof(float));  // g40 output Sn
    float* S4  = (float*)alloc((size_t)N * sizeof(float));  // hop1-40 output S
    int*   col    = (int*)alloc((size_t)E * sizeof(int));
    int*   deg    = (int*)alloc((size_t)N * sizeof(int));
    int*   rowptr = (int*)alloc((size_t)(N + 1) * sizeof(int));
    float* norm   = (float*)alloc((size_t)N * sizeof(float));
    int*   bsum   = (int*)alloc((size_t)(SBLK + 2) * sizeof(int));
    short* W1h = (short*)alloc(16384 * sizeof(short));
    short* W1l = (short*)alloc(16384 * sizeof(short));
    short* W2h = (short*)alloc(16384 * sizeof(short));
    short* W2l = (short*)alloc(16384 * sizeof(short));
    short* W3h = (short*)alloc(6144 * sizeof(short));
    short* W3l = (short*)alloc(6144 * sizeof(short));
    // aliases: rank -> QC (dead until k2-L1 writes it, fill runs before);
    // 40-wide buffers: G1 -> QB (dead after k2-L2), G2 -> QC (dead after gemm128-L2)
    int*   rank = (int*)QC;
    u32x2* G1 = (u32x2*)QB;
    u32x2* G2 = (u32x2*)QC;

    const int seg = (N + SBLK - 1) / SBLK;
    const int eblocks = (E + 255) / 256;

    // --- CSR build ---
    hipMemsetAsync(deg, 0, (size_t)N * sizeof(int), stream);
    deg_rank_kernel<<<eblocks, 256, 0, stream>>>(dst, deg, rank, E);
    scanA_kernel<<<SBLK, 256, 0, stream>>>(deg, rowptr, bsum, norm, N, seg);
    scanC_kernel<<<SBLK, 256, 0, stream>>>(rowptr, bsum, N, seg);
    fill_kernel<<<eblocks, 256, 0, stream>>>(src, dst, rowptr, rank, col, E);

    // --- W fragment prep + input quantization ---
    wprep_all<<<(38912 + 255) / 256, 256, 0, stream>>>(W1, W2, W3, W1h, W1l, W2h, W2l, W3h, W3l);
    {
        int waves2 = (N + 1) / 2;
        int xblocks = (waves2 * 64 + 255) / 256;
        xquant_kernel<<<xblocks, 256, 0, stream>>>((const float4*)features, norm, QA, Snx, N);
    }

    const int spmm_blocks = (N * 64 + 255) / 256;  // one wave per node
    const int gemm_blocks = (N + 63) / 64;

    // layer 1
    spmm128_q<1><<<spmm_blocks, 256, 0, stream>>>(QA, Snx, rowptr, col, norm, QB, Sk, N);
    spmm128_q<0><<<spmm_blocks, 256, 0, stream>>>(QB, Sk, rowptr, col, norm, QC, Sq2, N);
    gemm_mfma128<<<gemm_blocks, 256, 0, stream>>>((const unsigned short*)QC, Sq2,
                                                  (const short8v*)W1h, (const short8v*)W1l,
                                                  b1, norm, (unsigned short*)QA, Sg, Sng, N);

    // layer 2
    spmm128_q<1><<<spmm_blocks, 256, 0, stream>>>(QA, Sng, rowptr, col, norm, QB, Sk, N);
    spmm128_q<0><<<spmm_blocks, 256, 0, stream>>>(QB, Sk, rowptr, col, norm, QC, Sq2, N);
    gemm_mfma128<<<gemm_blocks, 256, 0, stream>>>((const unsigned short*)QC, Sq2,
                                                  (const short8v*)W2h, (const short8v*)W2l,
                                                  b2, norm, (unsigned short*)QA, Sg, Sng, N);

    // layer 3 (reordered): project 128->40 (int16 in/out), then 2 hops at 40-wide
    gemm_mfma40<<<gemm_blocks, 256, 0, stream>>>((const unsigned short*)QA, Sg,
                                                 (const short8v*)W3h, (const short8v*)W3l,
                                                 norm, (unsigned short*)G1, S3, Sn3, N);
    spmm40_q<0><<<spmm_blocks, 256, 0, stream>>>(G1, Sn3, rowptr, col, norm,
                                                 G2, S4, nullptr, nullptr, N);
    spmm40_q<1><<<spmm_blocks, 256, 0, stream>>>(G2, S4, rowptr, col, norm,
                                                 nullptr, nullptr, (f32x4*)out, b3, N);
}

// Round 11
// 615.880 us; speedup vs baseline: 1.1213x; 1.0184x over previous
//
#include <hip/hip_runtime.h>
#include <hip/hip_bf16.h>

// ---------------------------------------------------------------------------
// DeepSGC on MI355X:
//   - CSR build per call: ILP-4 rank-recording deg pass, 2-kernel scan,
//     ILP-4 atomic-free fill
//   - ALL hop traffic int16 row-quantized (128-wide: 256B/row; 40-wide: 80B/row)
//     with per-row scale S (dequant) and Sn = S*norm (fuses the norm gather-scale)
//   - hop pairs folded: k1: z = N^2 A (Sn gather); k2: y = N A z (S gather)
//   - 128-wide SpMM: unroll 8 interleaved + 1-iter col/esc software prefetch
//   - GEMMs: 3x bf16 MFMA split-precision, int16 A dequantized in-register
//   - layer-3 reorder: project 128->40 first, then 2 hops at 40-wide
// ---------------------------------------------------------------------------

typedef __attribute__((ext_vector_type(8))) short short8v;   // 8 x bf16
typedef __attribute__((ext_vector_type(4))) float f32x4;
typedef __attribute__((ext_vector_type(2))) unsigned int u32x2;

#define SBLK 128  // scan segments

__device__ __forceinline__ unsigned short f2bf(float x) {
    unsigned int u = __builtin_bit_cast(unsigned int, x);
    unsigned int r = u + 0x7fffu + ((u >> 16) & 1u);   // RNE
    return (unsigned short)(r >> 16);
}
__device__ __forceinline__ float bf2f(unsigned short h) {
    unsigned int u = ((unsigned int)h) << 16;
    return __builtin_bit_cast(float, u);
}

// ------------------------------- CSR build --------------------------------

// ILP-4: each thread handles 4 edges (int4 loads, 4 atomic-returns in flight).
__global__ void __launch_bounds__(256) deg_rank_kernel(const int* __restrict__ dst,
                                                       int* __restrict__ deg,
                                                       int* __restrict__ rank, int E) {
    int e = (blockIdx.x * blockDim.x + threadIdx.x) * 4;
    if (e + 4 <= E) {
        int4 d = *reinterpret_cast<const int4*>(dst + e);
        int r0 = atomicAdd(&deg[d.x], 1);
        int r1 = atomicAdd(&deg[d.y], 1);
        int r2 = atomicAdd(&deg[d.z], 1);
        int r3 = atomicAdd(&deg[d.w], 1);
        int4 r; r.x = r0; r.y = r1; r.z = r2; r.w = r3;
        *reinterpret_cast<int4*>(rank + e) = r;
    } else {
        for (; e < E; ++e) rank[e] = atomicAdd(&deg[dst[e]], 1);
    }
}

__global__ void __launch_bounds__(256) scanA_kernel(const int* __restrict__ deg,
                                                    int* __restrict__ rowptr,
                                                    int* __restrict__ bsum,
                                                    float* __restrict__ norm,
                                                    int n, int seg) {
    __shared__ int ws[4];
    __shared__ int carry;
    int b = blockIdx.x;
    int start = b * seg;
    int finish = start + seg; if (finish > n) finish = n;
    int t = threadIdx.x, lane = t & 63, w = t >> 6;
    if (t == 0) carry = 0;
    __syncthreads();
    for (int base = start; base < finish; base += 256) {
        int i = base + t;
        int v = 0;
        if (i < finish) {
            v = deg[i];
            norm[i] = rsqrtf((float)(v < 1 ? 1 : v));
        }
        int x = v;
        #pragma unroll
        for (int off = 1; off < 64; off <<= 1) {
            int y = __shfl_up(x, off, 64);
            if (lane >= off) x += y;
        }
        if (lane == 63) ws[w] = x;
        __syncthreads();
        int woff = 0;
        #pragma unroll
        for (int k = 0; k < 4; ++k) if (k < w) woff += ws[k];
        if (i < finish) rowptr[i] = carry + woff + x - v;
        int tot = ws[0] + ws[1] + ws[2] + ws[3];
        __syncthreads();
        if (t == 0) carry += tot;
        __syncthreads();
    }
    if (t == 0) bsum[b] = carry;
}

__global__ void __launch_bounds__(256) scanC_kernel(int* __restrict__ rowptr,
                                                    const int* __restrict__ bsum,
                                                    int n, int seg) {
    __shared__ int tmp[SBLK + 1];
    int b = blockIdx.x, t = threadIdx.x;
    if (t < SBLK) tmp[t] = bsum[t];
    __syncthreads();
    if (t == 0) {
        int s = 0;
        #pragma unroll 4
        for (int i = 0; i < SBLK; ++i) { int v = tmp[i]; tmp[i] = s; s += v; }
        tmp[SBLK] = s;
    }
    __syncthreads();
    int add = tmp[b];
    int start = b * seg;
    int finish = start + seg; if (finish > n) finish = n;
    for (int i = start + t; i < finish; i += 256) rowptr[i] += add;
    if (b == 0 && t == 0) rowptr[n] = tmp[SBLK];
}

// ILP-4 atomic-free fill: 4 edges/thread, int4 loads, 4 scatter stores.
__global__ void __launch_bounds__(256) fill_kernel(const int* __restrict__ src,
                                                   const int* __restrict__ dst,
                                                   const int* __restrict__ rowptr,
                                                   const int* __restrict__ rank,
                                                   int* __restrict__ col, int E) {
    int e = (blockIdx.x * blockDim.x + threadIdx.x) * 4;
    if (e + 4 <= E) {
        int4 d = *reinterpret_cast<const int4*>(dst + e);
        int4 r = *reinterpret_cast<const int4*>(rank + e);
        int4 s = *reinterpret_cast<const int4*>(src + e);
        int p0 = rowptr[d.x], p1 = rowptr[d.y], p2 = rowptr[d.z], p3 = rowptr[d.w];
        col[p0 + r.x] = s.x;
        col[p1 + r.y] = s.y;
        col[p2 + r.z] = s.z;
        col[p3 + r.w] = s.w;
    } else {
        for (; e < E; ++e) col[rowptr[dst[e]] + rank[e]] = src[e];
    }
}

// ------------------------ input row quantization ---------------------------

__global__ void __launch_bounds__(256) xquant_kernel(const float4* __restrict__ x,
                                                     const float* __restrict__ norm,
                                                     u32x2* __restrict__ xq,
                                                     float* __restrict__ Sn,
                                                     int n) {
    int gw = (blockIdx.x * blockDim.x + threadIdx.x) >> 6;
    int lane = threadIdx.x & 63, half = lane >> 5, l32 = lane & 31;
    int node = gw * 2 + half;
    if (node >= n) return;
    float4 v = x[(size_t)node * 32 + l32];
    float m = fmaxf(fmaxf(fabsf(v.x), fabsf(v.y)), fmaxf(fabsf(v.z), fabsf(v.w)));
    #pragma unroll
    for (int s = 1; s < 32; s <<= 1) m = fmaxf(m, __shfl_xor(m, s));
    float sraw = fmaxf(m, 1e-30f);
    float inv = 32767.f / sraw;
    float sv = sraw * (1.f / 32767.f);
    int a0 = (int)rintf(fminf(fmaxf(v.x * inv, -32767.f), 32767.f));
    int a1 = (int)rintf(fminf(fmaxf(v.y * inv, -32767.f), 32767.f));
    int a2 = (int)rintf(fminf(fmaxf(v.z * inv, -32767.f), 32767.f));
    int a3 = (int)rintf(fminf(fmaxf(v.w * inv, -32767.f), 32767.f));
    u32x2 p = {(unsigned)(a0 & 0xffff) | ((unsigned)a1 << 16),
               (unsigned)(a2 & 0xffff) | ((unsigned)a3 << 16)};
    __builtin_nontemporal_store(p, &xq[(size_t)node * 32 + l32]);
    if (l32 == 0) Sn[node] = sv * norm[node];
}

// --------------------------- 128-wide SpMM hops ----------------------------
// int16 gather: row = 32 x u32x2 (8B/lane, half-wave/row). 8 edges in flight
// per iter + next iteration's col/esc prefetched.
// SQ=1: k1, f=nv^2 (esc=Sn of producer). SQ=0: k2, f=nv (esc=S of k1).

template <int SQ>
__global__ void __launch_bounds__(256, 8) spmm128_q(const u32x2* __restrict__ hq,
                                                    const float* __restrict__ esc,
                                                    const int* __restrict__ rp,
                                                    const int* __restrict__ col,
                                                    const float* __restrict__ norm,
                                                    u32x2* __restrict__ outq,
                                                    float* __restrict__ So,
                                                    int n) {
    int wid = (blockIdx.x * blockDim.x + threadIdx.x) >> 6;
    if (wid >= n) return;
    int lane = threadIdx.x & 63, half = lane >> 5, l32 = lane & 31;
    int beg = rp[wid], end = rp[wid + 1];
    f32x4 acc = {0.f, 0.f, 0.f, 0.f};
    if (beg < end) {
        int last = end - 1;
        int u0, u1, u2, u3;
        float s0, s1, s2, s3;
        {
            int i0 = beg + half, i1 = beg + 2 + half, i2 = beg + 4 + half, i3 = beg + 6 + half;
            int i0c = i0 < end ? i0 : last;
            int i1c = i1 < end ? i1 : last;
            int i2c = i2 < end ? i2 : last;
            int i3c = i3 < end ? i3 : last;
            u0 = col[i0c]; u1 = col[i1c]; u2 = col[i2c]; u3 = col[i3c];
            s0 = i0 < end ? esc[u0] : 0.f;
            s1 = i1 < end ? esc[u1] : 0.f;
            s2 = i2 < end ? esc[u2] : 0.f;
            s3 = i3 < end ? esc[u3] : 0.f;
        }
        for (int e = beg; e < end; e += 8) {
            u32x2 q0 = hq[(size_t)u0 * 32 + l32];
            u32x2 q1 = hq[(size_t)u1 * 32 + l32];
            u32x2 q2 = hq[(size_t)u2 * 32 + l32];
            u32x2 q3 = hq[(size_t)u3 * 32 + l32];
            int en = e + 8;
            int j0 = en + half, j1 = en + 2 + half, j2 = en + 4 + half, j3 = en + 6 + half;
            int j0c = j0 < end ? j0 : last;
            int j1c = j1 < end ? j1 : last;
            int j2c = j2 < end ? j2 : last;
            int j3c = j3 < end ? j3 : last;
            int nu0 = col[j0c], nu1 = col[j1c], nu2 = col[j2c], nu3 = col[j3c];
            float ns0 = j0 < end ? esc[nu0] : 0.f;
            float ns1 = j1 < end ? esc[nu1] : 0.f;
            float ns2 = j2 < end ? esc[nu2] : 0.f;
            float ns3 = j3 < end ? esc[nu3] : 0.f;
            acc.x += (float)(short)(q0.x) * s0;
            acc.y += (float)((int)q0.x >> 16) * s0;
            acc.z += (float)(short)(q0.y) * s0;
            acc.w += (float)((int)q0.y >> 16) * s0;
            acc.x += (float)(short)(q1.x) * s1;
            acc.y += (float)((int)q1.x >> 16) * s1;
            acc.z += (float)(short)(q1.y) * s1;
            acc.w += (float)((int)q1.y >> 16) * s1;
            acc.x += (float)(short)(q2.x) * s2;
            acc.y += (float)((int)q2.x >> 16) * s2;
            acc.z += (float)(short)(q2.y) * s2;
            acc.w += (float)((int)q2.y >> 16) * s2;
            acc.x += (float)(short)(q3.x) * s3;
            acc.y += (float)((int)q3.x >> 16) * s3;
            acc.z += (float)(short)(q3.y) * s3;
            acc.w += (float)((int)q3.y >> 16) * s3;
            u0 = nu0; u1 = nu1; u2 = nu2; u3 = nu3;
            s0 = ns0; s1 = ns1; s2 = ns2; s3 = ns3;
        }
    }
    acc.x += __shfl_xor(acc.x, 32);
    acc.y += __shfl_xor(acc.y, 32);
    acc.z += __shfl_xor(acc.z, 32);
    acc.w += __shfl_xor(acc.w, 32);
    float nv = norm[wid];
    float f = SQ ? nv * nv : nv;
    acc.x *= f; acc.y *= f; acc.z *= f; acc.w *= f;
    float m = fmaxf(fmaxf(fabsf(acc.x), fabsf(acc.y)), fmaxf(fabsf(acc.z), fabsf(acc.w)));
    #pragma unroll
    for (int s = 1; s < 64; s <<= 1) m = fmaxf(m, __shfl_xor(m, s));
    float sraw = fmaxf(m, 1e-30f);
    float inv = 32767.f / sraw;
    float sv = sraw * (1.f / 32767.f);
    if (half == 0) {
        int a0 = (int)rintf(fminf(fmaxf(acc.x * inv, -32767.f), 32767.f));
        int a1 = (int)rintf(fminf(fmaxf(acc.y * inv, -32767.f), 32767.f));
        int a2 = (int)rintf(fminf(fmaxf(acc.z * inv, -32767.f), 32767.f));
        int a3 = (int)rintf(fminf(fmaxf(acc.w * inv, -32767.f), 32767.f));
        u32x2 p = {(unsigned)(a0 & 0xffff) | ((unsigned)a1 << 16),
                   (unsigned)(a2 & 0xffff) | ((unsigned)a3 << 16)};
        __builtin_nontemporal_store(p, &outq[(size_t)wid * 32 + l32]);
    }
    if (lane == 0) So[wid] = sv;
}

// ---------------------------- 40-wide SpMM hops ----------------------------

template <int EPI>  // 0: hop1 (esc=Sn3, f=nv^2, int16 out + S4); 1: hop2 (esc=S4, f=nv, f32 out + b3)
__global__ void __launch_bounds__(256, 8) spmm40_q(const u32x2* __restrict__ hq,
                                                   const float* __restrict__ esc,
                                                   const int* __restrict__ rp,
                                                   const int* __restrict__ col,
                                                   const float* __restrict__ norm,
                                                   u32x2* __restrict__ outq,
                                                   float* __restrict__ So,
                                                   f32x4* __restrict__ outf,
                                                   const float* __restrict__ b3,
                                                   int n) {
    int wid = (blockIdx.x * blockDim.x + threadIdx.x) >> 6;
    if (wid >= n) return;
    int lane = threadIdx.x & 63;
    int slot = lane / 10;      // 0..5 active; lanes 60-63 idle
    int t = lane % 10;
    bool active = slot < 6;
    int beg = rp[wid], end = rp[wid + 1];
    f32x4 acc = {0.f, 0.f, 0.f, 0.f};
    if (beg < end) {
        int last = end - 1;
        for (int base = beg; base < end; base += 18) {
            float s[3];
            u32x2 q[3];
            #pragma unroll
            for (int k = 0; k < 3; ++k) {
                int i = base + 6 * k + slot;
                int ic = (active && i < end) ? i : last;
                int u = col[ic];
                s[k] = (active && i < end) ? esc[u] : 0.f;
                q[k] = hq[(size_t)u * 10 + t];
            }
            #pragma unroll
            for (int k = 0; k < 3; ++k) {
                acc.x += (float)(short)(q[k].x) * s[k];
                acc.y += (float)((int)q[k].x >> 16) * s[k];
                acc.z += (float)(short)(q[k].y) * s[k];
                acc.w += (float)((int)q[k].y >> 16) * s[k];
            }
        }
    }
    f32x4 tot = acc;
    #pragma unroll
    for (int k = 1; k < 6; ++k) {
        int srcl = t + ((slot + k) % 6) * 10;
        tot.x += __shfl(acc.x, srcl);
        tot.y += __shfl(acc.y, srcl);
        tot.z += __shfl(acc.z, srcl);
        tot.w += __shfl(acc.w, srcl);
    }
    float nv = norm[wid];
    if (EPI == 0) {
        float f = nv * nv;
        f32x4 v = {tot.x * f, tot.y * f, tot.z * f, tot.w * f};
        float m = (slot < 6)
                ? fmaxf(fmaxf(fabsf(v.x), fabsf(v.y)), fmaxf(fabsf(v.z), fabsf(v.w)))
                : 0.f;
        #pragma unroll
        for (int s = 1; s < 64; s <<= 1) m = fmaxf(m, __shfl_xor(m, s));
        float sraw = fmaxf(m, 1e-30f);
        float inv = 32767.f / sraw;
        float sv = sraw * (1.f / 32767.f);
        if (slot == 0) {
            int a0 = (int)rintf(fminf(fmaxf(v.x * inv, -32767.f), 32767.f));
            int a1 = (int)rintf(fminf(fmaxf(v.y * inv, -32767.f), 32767.f));
            int a2 = (int)rintf(fminf(fmaxf(v.z * inv, -32767.f), 32767.f));
            int a3 = (int)rintf(fminf(fmaxf(v.w * inv, -32767.f), 32767.f));
            u32x2 p = {(unsigned)(a0 & 0xffff) | ((unsigned)a1 << 16),
                       (unsigned)(a2 & 0xffff) | ((unsigned)a3 << 16)};
            __builtin_nontemporal_store(p, &outq[(size_t)wid * 10 + t]);
        }
        if (lane == 0) So[wid] = sv;
    } else {
        if (slot == 0) {
            f32x4 bv = ((const f32x4*)b3)[t];
            f32x4 o = {tot.x * nv + bv.x, tot.y * nv + bv.y,
                       tot.z * nv + bv.z, tot.w * nv + bv.w};
            __builtin_nontemporal_store(o, &outf[(size_t)wid * 10 + t]);
        }
    }
}

// ------------------------- W fragment preparation --------------------------

__device__ __forceinline__ void wprep_one(const float* __restrict__ W,
                                          short* __restrict__ Wh,
                                          short* __restrict__ Wl,
                                          int ncols, int CF, int i) {
    int j = i & 7;
    int lane = (i >> 3) & 63;
    int f = i >> 9;
    int cf = f % CF, ks = f / CF;
    int k = ks * 32 + 8 * (lane >> 4) + j;
    int c = cf * 16 + (lane & 15);
    float v = (c < ncols) ? W[k * ncols + c] : 0.f;
    unsigned short h = f2bf(v);
    unsigned short l = f2bf(v - bf2f(h));
    Wh[i] = (short)h;
    Wl[i] = (short)l;
}

__global__ void __launch_bounds__(256) wprep_all(const float* __restrict__ W1,
                                                 const float* __restrict__ W2,
                                                 const float* __restrict__ W3,
                                                 short* __restrict__ W1h, short* __restrict__ W1l,
                                                 short* __restrict__ W2h, short* __restrict__ W2l,
                                                 short* __restrict__ W3h, short* __restrict__ W3l) {
    int i = blockIdx.x * blockDim.x + threadIdx.x;
    if (i < 16384) wprep_one(W1, W1h, W1l, 128, 8, i);
    else if (i < 32768) wprep_one(W2, W2h, W2l, 128, 8, i - 16384);
    else if (i < 38912) wprep_one(W3, W3h, W3l, 40, 3, i - 32768);
}

// ------------------------- split-bf16 MFMA GEMMs ---------------------------

__global__ void __launch_bounds__(256) gemm_mfma128(const unsigned short* __restrict__ Aq,
                                                    const float* __restrict__ SA,
                                                    const short8v* __restrict__ Wh,
                                                    const short8v* __restrict__ Wl,
                                                    const float* __restrict__ bias,
                                                    const float* __restrict__ norm,
                                                    unsigned short* __restrict__ Cq,
                                                    float* __restrict__ So,
                                                    float* __restrict__ Sno,
                                                    int n) {
    int lane = threadIdx.x & 63;
    int wid = threadIdx.x >> 6;
    int r0 = blockIdx.x * 64 + wid * 16;
    if (r0 >= n) return;
    int arow = r0 + (lane & 15);
    if (arow > n - 1) arow = n - 1;
    int kbase = 8 * (lane >> 4);
    float sA = SA[arow];
    f32x4 acc[8];
    #pragma unroll
    for (int i = 0; i < 8; ++i) acc[i] = (f32x4){0.f, 0.f, 0.f, 0.f};
    #pragma unroll
    for (int ks = 0; ks < 4; ++ks) {
        short8v qv = *(const short8v*)(Aq + (size_t)arow * 128 + ks * 32 + kbase);
        short8v ah, al;
        #pragma unroll
        for (int j = 0; j < 8; ++j) {
            float v = (float)qv[j] * sA;
            unsigned int uv = __builtin_bit_cast(unsigned int, v);
            unsigned short hi = (unsigned short)(uv >> 16);      // trunc bf16
            float r = v - bf2f(hi);
            ah[j] = (short)hi;
            al[j] = (short)f2bf(r);
        }
        #pragma unroll
        for (int cf = 0; cf < 8; ++cf) {
            short8v bh = Wh[(ks * 8 + cf) * 64 + lane];
            short8v bl = Wl[(ks * 8 + cf) * 64 + lane];
            acc[cf] = __builtin_amdgcn_mfma_f32_16x16x32_bf16(ah, bh, acc[cf], 0, 0, 0);
            acc[cf] = __builtin_amdgcn_mfma_f32_16x16x32_bf16(al, bh, acc[cf], 0, 0, 0);
            acc[cf] = __builtin_amdgcn_mfma_f32_16x16x32_bf16(ah, bl, acc[cf], 0, 0, 0);
        }
    }
    int rbase = r0 + (lane >> 4) * 4;
    int c0 = lane & 15;
    float bc[8];
    #pragma unroll
    for (int cf = 0; cf < 8; ++cf) bc[cf] = bias[cf * 16 + c0];

    float mq[4] = {0.f, 0.f, 0.f, 0.f};
    #pragma unroll
    for (int cf = 0; cf < 8; ++cf) {
        #pragma unroll
        for (int q = 0; q < 4; ++q)
            mq[q] = fmaxf(mq[q], fmaxf(acc[cf][q] + bc[cf], 0.f));
    }
    #pragma unroll
    for (int s = 1; s < 16; s <<= 1) {
        #pragma unroll
        for (int q = 0; q < 4; ++q) mq[q] = fmaxf(mq[q], __shfl_xor(mq[q], s));
    }
    float invq[4], svq[4];
    #pragma unroll
    for (int q = 0; q < 4; ++q) {
        float sraw = fmaxf(mq[q], 1e-30f);
        invq[q] = 32767.f / sraw;
        svq[q] = sraw * (1.f / 32767.f);
    }
    #pragma unroll
    for (int cf = 0; cf < 8; ++cf) {
        int colc = cf * 16 + c0;
        #pragma unroll
        for (int q = 0; q < 4; ++q) {
            int row = rbase + q;
            if (row >= n) continue;
            float v = fmaxf(acc[cf][q] + bc[cf], 0.f);
            int qi = (int)rintf(fminf(v * invq[q], 32767.f));  // v >= 0
            Cq[(size_t)row * 128 + colc] = (unsigned short)qi;
        }
    }
    if (c0 == 0) {
        #pragma unroll
        for (int q = 0; q < 4; ++q) {
            int row = rbase + q;
            if (row < n) { So[row] = svq[q]; Sno[row] = svq[q] * norm[row]; }
        }
    }
}

// 128->40: A from int16+scale; out int16 + S3/Sn3.
__global__ void __launch_bounds__(256) gemm_mfma40(const unsigned short* __restrict__ Aq,
                                                   const float* __restrict__ SA,
                                                   const short8v* __restrict__ Wh,
                                                   const short8v* __restrict__ Wl,
                                                   const float* __restrict__ norm,
                                                   unsigned short* __restrict__ Cq,
                                                   float* __restrict__ S3,
                                                   float* __restrict__ Sn3,
                                                   int n) {
    int lane = threadIdx.x & 63;
    int wid = threadIdx.x >> 6;
    int r0 = blockIdx.x * 64 + wid * 16;
    if (r0 >= n) return;
    int arow = r0 + (lane & 15);
    if (arow > n - 1) arow = n - 1;
    int kbase = 8 * (lane >> 4);
    float sA = SA[arow];
    f32x4 acc[3];
    #pragma unroll
    for (int i = 0; i < 3; ++i) acc[i] = (f32x4){0.f, 0.f, 0.f, 0.f};
    #pragma unroll
    for (int ks = 0; ks < 4; ++ks) {
        short8v qv = *(const short8v*)(Aq + (size_t)arow * 128 + ks * 32 + kbase);
        short8v ah, al;
        #pragma unroll
        for (int j = 0; j < 8; ++j) {
            float v = (float)qv[j] * sA;
            unsigned int uv = __builtin_bit_cast(unsigned int, v);
            unsigned short hi = (unsigned short)(uv >> 16);      // trunc bf16
            float r = v - bf2f(hi);
            ah[j] = (short)hi;
            al[j] = (short)f2bf(r);
        }
        #pragma unroll
        for (int cf = 0; cf < 3; ++cf) {
            short8v bh = Wh[(ks * 3 + cf) * 64 + lane];
            short8v bl = Wl[(ks * 3 + cf) * 64 + lane];
            acc[cf] = __builtin_amdgcn_mfma_f32_16x16x32_bf16(ah, bh, acc[cf], 0, 0, 0);
            acc[cf] = __builtin_amdgcn_mfma_f32_16x16x32_bf16(al, bh, acc[cf], 0, 0, 0);
            acc[cf] = __builtin_amdgcn_mfma_f32_16x16x32_bf16(ah, bl, acc[cf], 0, 0, 0);
        }
    }
    int rbase = r0 + (lane >> 4) * 4;
    int c0 = lane & 15;
    float mq[4] = {0.f, 0.f, 0.f, 0.f};
    #pragma unroll
    for (int cf = 0; cf < 3; ++cf) {
        int colc = cf * 16 + c0;
        if (colc < 40) {
            #pragma unroll
            for (int q = 0; q < 4; ++q) mq[q] = fmaxf(mq[q], fabsf(acc[cf][q]));
        }
    }
    #pragma unroll
    for (int s = 1; s < 16; s <<= 1) {
        #pragma unroll
        for (int q = 0; q < 4; ++q) mq[q] = fmaxf(mq[q], __shfl_xor(mq[q], s));
    }
    float invq[4], svq[4];
    #pragma unroll
    for (int q = 0; q < 4; ++q) {
        float sraw = fmaxf(mq[q], 1e-30f);
        invq[q] = 32767.f / sraw;
        svq[q] = sraw * (1.f / 32767.f);
    }
    #pragma unroll
    for (int cf = 0; cf < 3; ++cf) {
        int colc = cf * 16 + c0;
        if (colc >= 40) continue;
        #pragma unroll
        for (int q = 0; q < 4; ++q) {
            int row = rbase + q;
            if (row >= n) continue;
            float v = acc[cf][q];
            int qi = (int)rintf(fminf(fmaxf(v * invq[q], -32767.f), 32767.f));
            Cq[(size_t)row * 40 + colc] = (unsigned short)qi;
        }
    }
    if (c0 == 0) {
        #pragma unroll
        for (int q = 0; q < 4; ++q) {
            int row = rbase + q;
            if (row < n) { S3[row] = svq[q]; Sn3[row] = svq[q] * norm[row]; }
        }
    }
}

// --------------------------------- launch ----------------------------------

extern "C" void kernel_launch(void* const* d_in, const int* in_sizes, int n_in,
                              void* d_out, int out_size, void* d_ws, size_t ws_size,
                              hipStream_t stream) {
    const float* features = (const float*)d_in[0];
    const int*   src      = (const int*)d_in[1];
    const int*   dst      = (const int*)d_in[2];
    const float* W1 = (const float*)d_in[3];
    const float* b1 = (const float*)d_in[4];
    const float* W2 = (const float*)d_in[5];
    const float* b2 = (const float*)d_in[6];
    const float* W3 = (const float*)d_in[7];
    const float* b3 = (const float*)d_in[8];
    float* out = (float*)d_out;

    const int N = in_sizes[0] / 128;
    const int E = in_sizes[1];

    char* ws = (char*)d_ws;
    size_t off = 0;
    auto alloc = [&](size_t bytes) -> void* {
        void* p = ws + off;
        off += (bytes + 511) & ~(size_t)511;
        return p;
    };
    u32x2* QA = (u32x2*)alloc((size_t)N * 32 * sizeof(u32x2));
    u32x2* QB = (u32x2*)alloc((size_t)N * 32 * sizeof(u32x2));
    u32x2* QC = (u32x2*)alloc((size_t)N * 32 * sizeof(u32x2));
    float* Snx = (float*)alloc((size_t)N * sizeof(float));
    float* Sk  = (float*)alloc((size_t)N * sizeof(float));
    float* Sq2 = (float*)alloc((size_t)N * sizeof(float));
    float* Sg  = (float*)alloc((size_t)N * sizeof(float));
    float* Sng = (float*)alloc((size_t)N * sizeof(float));
    float* S3  = (float*)alloc((size_t)N * sizeof(float));
    float* Sn3 = (float*)alloc((size_t)N * sizeof(float));
    float* S4  = (float*)alloc((size_t)N * sizeof(float));
    int*   col    = (int*)alloc((size_t)E * sizeof(int));
    int*   deg    = (int*)alloc((size_t)N * sizeof(int));
    int*   rowptr = (int*)alloc((size_t)(N + 1) * sizeof(int));
    float* norm   = (float*)alloc((size_t)N * sizeof(float));
    int*   bsum   = (int*)alloc((size_t)(SBLK + 2) * sizeof(int));
    short* W1h = (short*)alloc(16384 * sizeof(short));
    short* W1l = (short*)alloc(16384 * sizeof(short));
    short* W2h = (short*)alloc(16384 * sizeof(short));
    short* W2l = (short*)alloc(16384 * sizeof(short));
    short* W3h = (short*)alloc(6144 * sizeof(short));
    short* W3l = (short*)alloc(6144 * sizeof(short));
    int*   rank = (int*)QC;
    u32x2* G1 = (u32x2*)QB;
    u32x2* G2 = (u32x2*)QC;

    const int seg = (N + SBLK - 1) / SBLK;
    const int eblocks4 = (E + 1023) / 1024;  // 4 edges/thread

    // --- CSR build ---
    hipMemsetAsync(deg, 0, (size_t)N * sizeof(int), stream);
    deg_rank_kernel<<<eblocks4, 256, 0, stream>>>(dst, deg, rank, E);
    scanA_kernel<<<SBLK, 256, 0, stream>>>(deg, rowptr, bsum, norm, N, seg);
    scanC_kernel<<<SBLK, 256, 0, stream>>>(rowptr, bsum, N, seg);
    fill_kernel<<<eblocks4, 256, 0, stream>>>(src, dst, rowptr, rank, col, E);

    // --- W fragment prep + input quantization ---
    wprep_all<<<(38912 + 255) / 256, 256, 0, stream>>>(W1, W2, W3, W1h, W1l, W2h, W2l, W3h, W3l);
    {
        int waves2 = (N + 1) / 2;
        int xblocks = (waves2 * 64 + 255) / 256;
        xquant_kernel<<<xblocks, 256, 0, stream>>>((const float4*)features, norm, QA, Snx, N);
    }

    const int spmm_blocks = (N * 64 + 255) / 256;  // one wave per node
    const int gemm_blocks = (N + 63) / 64;

    // layer 1
    spmm128_q<1><<<spmm_blocks, 256, 0, stream>>>(QA, Snx, rowptr, col, norm, QB, Sk, N);
    spmm128_q<0><<<spmm_blocks, 256, 0, stream>>>(QB, Sk, rowptr, col, norm, QC, Sq2, N);
    gemm_mfma128<<<gemm_blocks, 256, 0, stream>>>((const unsigned short*)QC, Sq2,
                                                  (const short8v*)W1h, (const short8v*)W1l,
                                                  b1, norm, (unsigned short*)QA, Sg, Sng, N);

    // layer 2
    spmm128_q<1><<<spmm_blocks, 256, 0, stream>>>(QA, Sng, rowptr, col, norm, QB, Sk, N);
    spmm128_q<0><<<spmm_blocks, 256, 0, stream>>>(QB, Sk, rowptr, col, norm, QC, Sq2, N);
    gemm_mfma128<<<gemm_blocks, 256, 0, stream>>>((const unsigned short*)QC, Sq2,
                                                  (const short8v*)W2h, (const short8v*)W2l,
                                                  b2, norm, (unsigned short*)QA, Sg, Sng, N);

    // layer 3 (reordered): project 128->40 (int16 in/out), then 2 hops at 40-wide
    gemm_mfma40<<<gemm_blocks, 256, 0, stream>>>((const unsigned short*)QA, Sg,
                                                 (const short8v*)W3h, (const short8v*)W3l,
                                                 norm, (unsigned short*)G1, S3, Sn3, N);
    spmm40_q<0><<<spmm_blocks, 256, 0, stream>>>(G1, Sn3, rowptr, col, norm,
                                                 G2, S4, nullptr, nullptr, N);
    spmm40_q<1><<<spmm_blocks, 256, 0, stream>>>(G2, S4, rowptr, col, norm,
                                                 nullptr, nullptr, (f32x4*)out, b3, N);
}

// Round 13
// 566.394 us; speedup vs baseline: 1.2193x; 1.0874x over previous
//
#include <hip/hip_runtime.h>
#include <hip/hip_bf16.h>

// ---------------------------------------------------------------------------
// DeepSGC on MI355X:
//   - CSR build per call: ILP-4 rank-recording deg pass, 2-kernel scan,
//     ILP-4 atomic-free fill
//   - ALL hop traffic int16 row-quantized (128-wide: 256B/row; 40-wide: 80B/row)
//     with per-row scale S (dequant) and Sn = S*norm (fuses the norm gather-scale)
//   - hop pairs folded: k1: z = N^2 A (Sn gather); k2: y = N A z (S gather)
//   - 128-wide SpMM: quarter-wave 16B/lane gather (4 edge-slots/wave),
//     8 edges in flight + 1-iter col/esc software prefetch
//   - GEMMs: 3x bf16 MFMA split-precision, int16 A dequantized in-register
//   - layer-3 reorder: project 128->40 first, then 2 hops at 40-wide
// ---------------------------------------------------------------------------

typedef __attribute__((ext_vector_type(8))) short short8v;   // 8 x bf16
typedef __attribute__((ext_vector_type(4))) float f32x4;
typedef __attribute__((ext_vector_type(2))) unsigned int u32x2;
typedef __attribute__((ext_vector_type(4))) unsigned int u32x4;

#define SBLK 128  // scan segments

__device__ __forceinline__ unsigned short f2bf(float x) {
    unsigned int u = __builtin_bit_cast(unsigned int, x);
    unsigned int r = u + 0x7fffu + ((u >> 16) & 1u);   // RNE
    return (unsigned short)(r >> 16);
}
__device__ __forceinline__ float bf2f(unsigned short h) {
    unsigned int u = ((unsigned int)h) << 16;
    return __builtin_bit_cast(float, u);
}

// ------------------------------- CSR build --------------------------------

// ILP-4: each thread handles 4 edges (int4 loads, 4 atomic-returns in flight).
__global__ void __launch_bounds__(256) deg_rank_kernel(const int* __restrict__ dst,
                                                       int* __restrict__ deg,
                                                       int* __restrict__ rank, int E) {
    int e = (blockIdx.x * blockDim.x + threadIdx.x) * 4;
    if (e + 4 <= E) {
        int4 d = *reinterpret_cast<const int4*>(dst + e);
        int r0 = atomicAdd(&deg[d.x], 1);
        int r1 = atomicAdd(&deg[d.y], 1);
        int r2 = atomicAdd(&deg[d.z], 1);
        int r3 = atomicAdd(&deg[d.w], 1);
        int4 r; r.x = r0; r.y = r1; r.z = r2; r.w = r3;
        *reinterpret_cast<int4*>(rank + e) = r;
    } else {
        for (; e < E; ++e) rank[e] = atomicAdd(&deg[dst[e]], 1);
    }
}

__global__ void __launch_bounds__(256) scanA_kernel(const int* __restrict__ deg,
                                                    int* __restrict__ rowptr,
                                                    int* __restrict__ bsum,
                                                    float* __restrict__ norm,
                                                    int n, int seg) {
    __shared__ int ws[4];
    __shared__ int carry;
    int b = blockIdx.x;
    int start = b * seg;
    int finish = start + seg; if (finish > n) finish = n;
    int t = threadIdx.x, lane = t & 63, w = t >> 6;
    if (t == 0) carry = 0;
    __syncthreads();
    for (int base = start; base < finish; base += 256) {
        int i = base + t;
        int v = 0;
        if (i < finish) {
            v = deg[i];
            norm[i] = rsqrtf((float)(v < 1 ? 1 : v));
        }
        int x = v;
        #pragma unroll
        for (int off = 1; off < 64; off <<= 1) {
            int y = __shfl_up(x, off, 64);
            if (lane >= off) x += y;
        }
        if (lane == 63) ws[w] = x;
        __syncthreads();
        int woff = 0;
        #pragma unroll
        for (int k = 0; k < 4; ++k) if (k < w) woff += ws[k];
        if (i < finish) rowptr[i] = carry + woff + x - v;
        int tot = ws[0] + ws[1] + ws[2] + ws[3];
        __syncthreads();
        if (t == 0) carry += tot;
        __syncthreads();
    }
    if (t == 0) bsum[b] = carry;
}

__global__ void __launch_bounds__(256) scanC_kernel(int* __restrict__ rowptr,
                                                    const int* __restrict__ bsum,
                                                    int n, int seg) {
    __shared__ int tmp[SBLK + 1];
    int b = blockIdx.x, t = threadIdx.x;
    if (t < SBLK) tmp[t] = bsum[t];
    __syncthreads();
    if (t == 0) {
        int s = 0;
        #pragma unroll 4
        for (int i = 0; i < SBLK; ++i) { int v = tmp[i]; tmp[i] = s; s += v; }
        tmp[SBLK] = s;
    }
    __syncthreads();
    int add = tmp[b];
    int start = b * seg;
    int finish = start + seg; if (finish > n) finish = n;
    for (int i = start + t; i < finish; i += 256) rowptr[i] += add;
    if (b == 0 && t == 0) rowptr[n] = tmp[SBLK];
}

// ILP-4 atomic-free fill: 4 edges/thread, int4 loads, 4 scatter stores.
__global__ void __launch_bounds__(256) fill_kernel(const int* __restrict__ src,
                                                   const int* __restrict__ dst,
                                                   const int* __restrict__ rowptr,
                                                   const int* __restrict__ rank,
                                                   int* __restrict__ col, int E) {
    int e = (blockIdx.x * blockDim.x + threadIdx.x) * 4;
    if (e + 4 <= E) {
        int4 d = *reinterpret_cast<const int4*>(dst + e);
        int4 r = *reinterpret_cast<const int4*>(rank + e);
        int4 s = *reinterpret_cast<const int4*>(src + e);
        int p0 = rowptr[d.x], p1 = rowptr[d.y], p2 = rowptr[d.z], p3 = rowptr[d.w];
        col[p0 + r.x] = s.x;
        col[p1 + r.y] = s.y;
        col[p2 + r.z] = s.z;
        col[p3 + r.w] = s.w;
    } else {
        for (; e < E; ++e) col[rowptr[dst[e]] + rank[e]] = src[e];
    }
}

// ------------------------ input row quantization ---------------------------

__global__ void __launch_bounds__(256) xquant_kernel(const float4* __restrict__ x,
                                                     const float* __restrict__ norm,
                                                     u32x2* __restrict__ xq,
                                                     float* __restrict__ Sn,
                                                     int n) {
    int gw = (blockIdx.x * blockDim.x + threadIdx.x) >> 6;
    int lane = threadIdx.x & 63, half = lane >> 5, l32 = lane & 31;
    int node = gw * 2 + half;
    if (node >= n) return;
    float4 v = x[(size_t)node * 32 + l32];
    float m = fmaxf(fmaxf(fabsf(v.x), fabsf(v.y)), fmaxf(fabsf(v.z), fabsf(v.w)));
    #pragma unroll
    for (int s = 1; s < 32; s <<= 1) m = fmaxf(m, __shfl_xor(m, s));
    float sraw = fmaxf(m, 1e-30f);
    float inv = 32767.f / sraw;
    float sv = sraw * (1.f / 32767.f);
    int a0 = (int)rintf(fminf(fmaxf(v.x * inv, -32767.f), 32767.f));
    int a1 = (int)rintf(fminf(fmaxf(v.y * inv, -32767.f), 32767.f));
    int a2 = (int)rintf(fminf(fmaxf(v.z * inv, -32767.f), 32767.f));
    int a3 = (int)rintf(fminf(fmaxf(v.w * inv, -32767.f), 32767.f));
    u32x2 p = {(unsigned)(a0 & 0xffff) | ((unsigned)a1 << 16),
               (unsigned)(a2 & 0xffff) | ((unsigned)a3 << 16)};
    __builtin_nontemporal_store(p, &xq[(size_t)node * 32 + l32]);
    if (l32 == 0) Sn[node] = sv * norm[node];
}

// --------------------------- 128-wide SpMM hops ----------------------------
// Quarter-wave 16B/lane gather: row = 16 lanes x u32x4. 4 edge-slots (quads)
// per wave, unroll 2 -> 8 edges in flight; next iteration's col/esc prefetched.
// SQ=1: k1, f=nv^2 (esc=Sn of producer). SQ=0: k2, f=nv (esc=S of k1).
// Output: int16 row + per-row scale S.

template <int SQ>
__global__ void __launch_bounds__(256, 8) spmm128_q(const u32x4* __restrict__ hq,
                                                    const float* __restrict__ esc,
                                                    const int* __restrict__ rp,
                                                    const int* __restrict__ col,
                                                    const float* __restrict__ norm,
                                                    u32x4* __restrict__ outq,
                                                    float* __restrict__ So,
                                                    int n) {
    int wid = (blockIdx.x * blockDim.x + threadIdx.x) >> 6;
    if (wid >= n) return;
    int lane = threadIdx.x & 63;
    int quad = lane >> 4;      // 0..3 edge slot
    int l16 = lane & 15;       // 16B chunk within the 256B row
    int beg = rp[wid], end = rp[wid + 1];
    float acc[8] = {0.f, 0.f, 0.f, 0.f, 0.f, 0.f, 0.f, 0.f};
    if (beg < end) {
        int last = end - 1;
        int u0, u1;
        float s0, s1;
        {
            int i0 = beg + quad, i1 = beg + 4 + quad;
            int i0c = i0 < end ? i0 : last;
            int i1c = i1 < end ? i1 : last;
            u0 = col[i0c]; u1 = col[i1c];
            s0 = i0 < end ? esc[u0] : 0.f;
            s1 = i1 < end ? esc[u1] : 0.f;
        }
        for (int e = beg; e < end; e += 8) {
            u32x4 q0 = hq[(size_t)u0 * 16 + l16];
            u32x4 q1 = hq[(size_t)u1 * 16 + l16];
            // prefetch next iteration's col + esc (under the gathers)
            int en = e + 8;
            int j0 = en + quad, j1 = en + 4 + quad;
            int j0c = j0 < end ? j0 : last;
            int j1c = j1 < end ? j1 : last;
            int nu0 = col[j0c], nu1 = col[j1c];
            float ns0 = j0 < end ? esc[nu0] : 0.f;
            float ns1 = j1 < end ? esc[nu1] : 0.f;
            // accumulate 8 elements per edge slot
            acc[0] += (float)(short)(q0.x) * s0;
            acc[1] += (float)((int)q0.x >> 16) * s0;
            acc[2] += (float)(short)(q0.y) * s0;
            acc[3] += (float)((int)q0.y >> 16) * s0;
            acc[4] += (float)(short)(q0.z) * s0;
            acc[5] += (float)((int)q0.z >> 16) * s0;
            acc[6] += (float)(short)(q0.w) * s0;
            acc[7] += (float)((int)q0.w >> 16) * s0;
            acc[0] += (float)(short)(q1.x) * s1;
            acc[1] += (float)((int)q1.x >> 16) * s1;
            acc[2] += (float)(short)(q1.y) * s1;
            acc[3] += (float)((int)q1.y >> 16) * s1;
            acc[4] += (float)(short)(q1.z) * s1;
            acc[5] += (float)((int)q1.z >> 16) * s1;
            acc[6] += (float)(short)(q1.w) * s1;
            acc[7] += (float)((int)q1.w >> 16) * s1;
            u0 = nu0; u1 = nu1;
            s0 = ns0; s1 = ns1;
        }
    }
    // reduce across the 4 quads (all lanes participate; result replicated)
    #pragma unroll
    for (int j = 0; j < 8; ++j) {
        acc[j] += __shfl_xor(acc[j], 16);
        acc[j] += __shfl_xor(acc[j], 32);
    }
    float nv = norm[wid];
    float f = SQ ? nv * nv : nv;
    float m = 0.f;
    #pragma unroll
    for (int j = 0; j < 8; ++j) {
        acc[j] *= f;
        m = fmaxf(m, fabsf(acc[j]));
    }
    #pragma unroll
    for (int s = 1; s < 16; s <<= 1) m = fmaxf(m, __shfl_xor(m, s));
    float sraw = fmaxf(m, 1e-30f);
    float inv = 32767.f / sraw;
    float sv = sraw * (1.f / 32767.f);
    if (quad == 0) {
        int a[8];
        #pragma unroll
        for (int j = 0; j < 8; ++j)
            a[j] = (int)rintf(fminf(fmaxf(acc[j] * inv, -32767.f), 32767.f));
        u32x4 p;
        p.x = (unsigned)(a[0] & 0xffff) | ((unsigned)a[1] << 16);
        p.y = (unsigned)(a[2] & 0xffff) | ((unsigned)a[3] << 16);
        p.z = (unsigned)(a[4] & 0xffff) | ((unsigned)a[5] << 16);
        p.w = (unsigned)(a[6] & 0xffff) | ((unsigned)a[7] << 16);
        __builtin_nontemporal_store(p, &outq[(size_t)wid * 16 + l16]);
    }
    if (lane == 0) So[wid] = sv;
}

// ---------------------------- 40-wide SpMM hops ----------------------------
// int16 rows: 40 int16 = 10 x u32x2 per row. 6 edge-slots x 10 lanes,
// 18 edges in flight.

template <int EPI>  // 0: hop1 (esc=Sn3, f=nv^2, int16 out + S4); 1: hop2 (esc=S4, f=nv, f32 out + b3)
__global__ void __launch_bounds__(256, 8) spmm40_q(const u32x2* __restrict__ hq,
                                                   const float* __restrict__ esc,
                                                   const int* __restrict__ rp,
                                                   const int* __restrict__ col,
                                                   const float* __restrict__ norm,
                                                   u32x2* __restrict__ outq,
                                                   float* __restrict__ So,
                                                   f32x4* __restrict__ outf,
                                                   const float* __restrict__ b3,
                                                   int n) {
    int wid = (blockIdx.x * blockDim.x + threadIdx.x) >> 6;
    if (wid >= n) return;
    int lane = threadIdx.x & 63;
    int slot = lane / 10;      // 0..5 active; lanes 60-63 idle
    int t = lane % 10;
    bool active = slot < 6;
    int beg = rp[wid], end = rp[wid + 1];
    f32x4 acc = {0.f, 0.f, 0.f, 0.f};
    if (beg < end) {
        int last = end - 1;
        for (int base = beg; base < end; base += 18) {
            float s[3];
            u32x2 q[3];
            #pragma unroll
            for (int k = 0; k < 3; ++k) {
                int i = base + 6 * k + slot;
                int ic = (active && i < end) ? i : last;
                int u = col[ic];
                s[k] = (active && i < end) ? esc[u] : 0.f;
                q[k] = hq[(size_t)u * 10 + t];
            }
            #pragma unroll
            for (int k = 0; k < 3; ++k) {
                acc.x += (float)(short)(q[k].x) * s[k];
                acc.y += (float)((int)q[k].x >> 16) * s[k];
                acc.z += (float)(short)(q[k].y) * s[k];
                acc.w += (float)((int)q[k].y >> 16) * s[k];
            }
        }
    }
    f32x4 tot = acc;
    #pragma unroll
    for (int k = 1; k < 6; ++k) {
        int srcl = t + ((slot + k) % 6) * 10;
        tot.x += __shfl(acc.x, srcl);
        tot.y += __shfl(acc.y, srcl);
        tot.z += __shfl(acc.z, srcl);
        tot.w += __shfl(acc.w, srcl);
    }
    float nv = norm[wid];
    if (EPI == 0) {
        float f = nv * nv;
        f32x4 v = {tot.x * f, tot.y * f, tot.z * f, tot.w * f};
        float m = (slot < 6)
                ? fmaxf(fmaxf(fabsf(v.x), fabsf(v.y)), fmaxf(fabsf(v.z), fabsf(v.w)))
                : 0.f;
        #pragma unroll
        for (int s = 1; s < 64; s <<= 1) m = fmaxf(m, __shfl_xor(m, s));
        float sraw = fmaxf(m, 1e-30f);
        float inv = 32767.f / sraw;
        float sv = sraw * (1.f / 32767.f);
        if (slot == 0) {
            int a0 = (int)rintf(fminf(fmaxf(v.x * inv, -32767.f), 32767.f));
            int a1 = (int)rintf(fminf(fmaxf(v.y * inv, -32767.f), 32767.f));
            int a2 = (int)rintf(fminf(fmaxf(v.z * inv, -32767.f), 32767.f));
            int a3 = (int)rintf(fminf(fmaxf(v.w * inv, -32767.f), 32767.f));
            u32x2 p = {(unsigned)(a0 & 0xffff) | ((unsigned)a1 << 16),
                       (unsigned)(a2 & 0xffff) | ((unsigned)a3 << 16)};
            __builtin_nontemporal_store(p, &outq[(size_t)wid * 10 + t]);
        }
        if (lane == 0) So[wid] = sv;
    } else {
        if (slot == 0) {
            f32x4 bv = ((const f32x4*)b3)[t];
            f32x4 o = {tot.x * nv + bv.x, tot.y * nv + bv.y,
                       tot.z * nv + bv.z, tot.w * nv + bv.w};
            __builtin_nontemporal_store(o, &outf[(size_t)wid * 10 + t]);
        }
    }
}

// ------------------------- W fragment preparation --------------------------

__device__ __forceinline__ void wprep_one(const float* __restrict__ W,
                                          short* __restrict__ Wh,
                                          short* __restrict__ Wl,
                                          int ncols, int CF, int i) {
    int j = i & 7;
    int lane = (i >> 3) & 63;
    int f = i >> 9;
    int cf = f % CF, ks = f / CF;
    int k = ks * 32 + 8 * (lane >> 4) + j;
    int c = cf * 16 + (lane & 15);
    float v = (c < ncols) ? W[k * ncols + c] : 0.f;
    unsigned short h = f2bf(v);
    unsigned short l = f2bf(v - bf2f(h));
    Wh[i] = (short)h;
    Wl[i] = (short)l;
}

__global__ void __launch_bounds__(256) wprep_all(const float* __restrict__ W1,
                                                 const float* __restrict__ W2,
                                                 const float* __restrict__ W3,
                                                 short* __restrict__ W1h, short* __restrict__ W1l,
                                                 short* __restrict__ W2h, short* __restrict__ W2l,
                                                 short* __restrict__ W3h, short* __restrict__ W3l) {
    int i = blockIdx.x * blockDim.x + threadIdx.x;
    if (i < 16384) wprep_one(W1, W1h, W1l, 128, 8, i);
    else if (i < 32768) wprep_one(W2, W2h, W2l, 128, 8, i - 16384);
    else if (i < 38912) wprep_one(W3, W3h, W3l, 40, 3, i - 32768);
}

// ------------------------- split-bf16 MFMA GEMMs ---------------------------

__global__ void __launch_bounds__(256) gemm_mfma128(const unsigned short* __restrict__ Aq,
                                                    const float* __restrict__ SA,
                                                    const short8v* __restrict__ Wh,
                                                    const short8v* __restrict__ Wl,
                                                    const float* __restrict__ bias,
                                                    const float* __restrict__ norm,
                                                    unsigned short* __restrict__ Cq,
                                                    float* __restrict__ So,
                                                    float* __restrict__ Sno,
                                                    int n) {
    int lane = threadIdx.x & 63;
    int wid = threadIdx.x >> 6;
    int r0 = blockIdx.x * 64 + wid * 16;
    if (r0 >= n) return;
    int arow = r0 + (lane & 15);
    if (arow > n - 1) arow = n - 1;
    int kbase = 8 * (lane >> 4);
    float sA = SA[arow];
    f32x4 acc[8];
    #pragma unroll
    for (int i = 0; i < 8; ++i) acc[i] = (f32x4){0.f, 0.f, 0.f, 0.f};
    #pragma unroll
    for (int ks = 0; ks < 4; ++ks) {
        short8v qv = *(const short8v*)(Aq + (size_t)arow * 128 + ks * 32 + kbase);
        short8v ah, al;
        #pragma unroll
        for (int j = 0; j < 8; ++j) {
            float v = (float)qv[j] * sA;
            unsigned int uv = __builtin_bit_cast(unsigned int, v);
            unsigned short hi = (unsigned short)(uv >> 16);      // trunc bf16
            float r = v - bf2f(hi);
            ah[j] = (short)hi;
            al[j] = (short)f2bf(r);
        }
        #pragma unroll
        for (int cf = 0; cf < 8; ++cf) {
            short8v bh = Wh[(ks * 8 + cf) * 64 + lane];
            short8v bl = Wl[(ks * 8 + cf) * 64 + lane];
            acc[cf] = __builtin_amdgcn_mfma_f32_16x16x32_bf16(ah, bh, acc[cf], 0, 0, 0);
            acc[cf] = __builtin_amdgcn_mfma_f32_16x16x32_bf16(al, bh, acc[cf], 0, 0, 0);
            acc[cf] = __builtin_amdgcn_mfma_f32_16x16x32_bf16(ah, bl, acc[cf], 0, 0, 0);
        }
    }
    int rbase = r0 + (lane >> 4) * 4;
    int c0 = lane & 15;
    float bc[8];
    #pragma unroll
    for (int cf = 0; cf < 8; ++cf) bc[cf] = bias[cf * 16 + c0];

    float mq[4] = {0.f, 0.f, 0.f, 0.f};
    #pragma unroll
    for (int cf = 0; cf < 8; ++cf) {
        #pragma unroll
        for (int q = 0; q < 4; ++q)
            mq[q] = fmaxf(mq[q], fmaxf(acc[cf][q] + bc[cf], 0.f));
    }
    #pragma unroll
    for (int s = 1; s < 16; s <<= 1) {
        #pragma unroll
        for (int q = 0; q < 4; ++q) mq[q] = fmaxf(mq[q], __shfl_xor(mq[q], s));
    }
    float invq[4], svq[4];
    #pragma unroll
    for (int q = 0; q < 4; ++q) {
        float sraw = fmaxf(mq[q], 1e-30f);
        invq[q] = 32767.f / sraw;
        svq[q] = sraw * (1.f / 32767.f);
    }
    #pragma unroll
    for (int cf = 0; cf < 8; ++cf) {
        int colc = cf * 16 + c0;
        #pragma unroll
        for (int q = 0; q < 4; ++q) {
            int row = rbase + q;
            if (row >= n) continue;
            float v = fmaxf(acc[cf][q] + bc[cf], 0.f);
            int qi = (int)rintf(fminf(v * invq[q], 32767.f));  // v >= 0
            Cq[(size_t)row * 128 + colc] = (unsigned short)qi;
        }
    }
    if (c0 == 0) {
        #pragma unroll
        for (int q = 0; q < 4; ++q) {
            int row = rbase + q;
            if (row < n) { So[row] = svq[q]; Sno[row] = svq[q] * norm[row]; }
        }
    }
}

// 128->40: A from int16+scale; out int16 + S3/Sn3.
__global__ void __launch_bounds__(256) gemm_mfma40(const unsigned short* __restrict__ Aq,
                                                   const float* __restrict__ SA,
                                                   const short8v* __restrict__ Wh,
                                                   const short8v* __restrict__ Wl,
                                                   const float* __restrict__ norm,
                                                   unsigned short* __restrict__ Cq,
                                                   float* __restrict__ S3,
                                                   float* __restrict__ Sn3,
                                                   int n) {
    int lane = threadIdx.x & 63;
    int wid = threadIdx.x >> 6;
    int r0 = blockIdx.x * 64 + wid * 16;
    if (r0 >= n) return;
    int arow = r0 + (lane & 15);
    if (arow > n - 1) arow = n - 1;
    int kbase = 8 * (lane >> 4);
    float sA = SA[arow];
    f32x4 acc[3];
    #pragma unroll
    for (int i = 0; i < 3; ++i) acc[i] = (f32x4){0.f, 0.f, 0.f, 0.f};
    #pragma unroll
    for (int ks = 0; ks < 4; ++ks) {
        short8v qv = *(const short8v*)(Aq + (size_t)arow * 128 + ks * 32 + kbase);
        short8v ah, al;
        #pragma unroll
        for (int j = 0; j < 8; ++j) {
            float v = (float)qv[j] * sA;
            unsigned int uv = __builtin_bit_cast(unsigned int, v);
            unsigned short hi = (unsigned short)(uv >> 16);      // trunc bf16
            float r = v - bf2f(hi);
            ah[j] = (short)hi;
            al[j] = (short)f2bf(r);
        }
        #pragma unroll
        for (int cf = 0; cf < 3; ++cf) {
            short8v bh = Wh[(ks * 3 + cf) * 64 + lane];
            short8v bl = Wl[(ks * 3 + cf) * 64 + lane];
            acc[cf] = __builtin_amdgcn_mfma_f32_16x16x32_bf16(ah, bh, acc[cf], 0, 0, 0);
            acc[cf] = __builtin_amdgcn_mfma_f32_16x16x32_bf16(al, bh, acc[cf], 0, 0, 0);
            acc[cf] = __builtin_amdgcn_mfma_f32_16x16x32_bf16(ah, bl, acc[cf], 0, 0, 0);
        }
    }
    int rbase = r0 + (lane >> 4) * 4;
    int c0 = lane & 15;
    float mq[4] = {0.f, 0.f, 0.f, 0.f};
    #pragma unroll
    for (int cf = 0; cf < 3; ++cf) {
        int colc = cf * 16 + c0;
        if (colc < 40) {
            #pragma unroll
            for (int q = 0; q < 4; ++q) mq[q] = fmaxf(mq[q], fabsf(acc[cf][q]));
        }
    }
    #pragma unroll
    for (int s = 1; s < 16; s <<= 1) {
        #pragma unroll
        for (int q = 0; q < 4; ++q) mq[q] = fmaxf(mq[q], __shfl_xor(mq[q], s));
    }
    float invq[4], svq[4];
    #pragma unroll
    for (int q = 0; q < 4; ++q) {
        float sraw = fmaxf(mq[q], 1e-30f);
        invq[q] = 32767.f / sraw;
        svq[q] = sraw * (1.f / 32767.f);
    }
    #pragma unroll
    for (int cf = 0; cf < 3; ++cf) {
        int colc = cf * 16 + c0;
        if (colc >= 40) continue;
        #pragma unroll
        for (int q = 0; q < 4; ++q) {
            int row = rbase + q;
            if (row >= n) continue;
            float v = acc[cf][q];
            int qi = (int)rintf(fminf(fmaxf(v * invq[q], -32767.f), 32767.f));
            Cq[(size_t)row * 40 + colc] = (unsigned short)qi;
        }
    }
    if (c0 == 0) {
        #pragma unroll
        for (int q = 0; q < 4; ++q) {
            int row = rbase + q;
            if (row < n) { S3[row] = svq[q]; Sn3[row] = svq[q] * norm[row]; }
        }
    }
}

// --------------------------------- launch ----------------------------------

extern "C" void kernel_launch(void* const* d_in, const int* in_sizes, int n_in,
                              void* d_out, int out_size, void* d_ws, size_t ws_size,
                              hipStream_t stream) {
    const float* features = (const float*)d_in[0];
    const int*   src      = (const int*)d_in[1];
    const int*   dst      = (const int*)d_in[2];
    const float* W1 = (const float*)d_in[3];
    const float* b1 = (const float*)d_in[4];
    const float* W2 = (const float*)d_in[5];
    const float* b2 = (const float*)d_in[6];
    const float* W3 = (const float*)d_in[7];
    const float* b3 = (const float*)d_in[8];
    float* out = (float*)d_out;

    const int N = in_sizes[0] / 128;
    const int E = in_sizes[1];

    char* ws = (char*)d_ws;
    size_t off = 0;
    auto alloc = [&](size_t bytes) -> void* {
        void* p = ws + off;
        off += (bytes + 511) & ~(size_t)511;
        return p;
    };
    u32x2* QA = (u32x2*)alloc((size_t)N * 32 * sizeof(u32x2));
    u32x2* QB = (u32x2*)alloc((size_t)N * 32 * sizeof(u32x2));
    u32x2* QC = (u32x2*)alloc((size_t)N * 32 * sizeof(u32x2));
    float* Snx = (float*)alloc((size_t)N * sizeof(float));
    float* Sk  = (float*)alloc((size_t)N * sizeof(float));
    float* Sq2 = (float*)alloc((size_t)N * sizeof(float));
    float* Sg  = (float*)alloc((size_t)N * sizeof(float));
    float* Sng = (float*)alloc((size_t)N * sizeof(float));
    float* S3  = (float*)alloc((size_t)N * sizeof(float));
    float* Sn3 = (float*)alloc((size_t)N * sizeof(float));
    float* S4  = (float*)alloc((size_t)N * sizeof(float));
    int*   col    = (int*)alloc((size_t)E * sizeof(int));
    int*   deg    = (int*)alloc((size_t)N * sizeof(int));
    int*   rowptr = (int*)alloc((size_t)(N + 1) * sizeof(int));
    float* norm   = (float*)alloc((size_t)N * sizeof(float));
    int*   bsum   = (int*)alloc((size_t)(SBLK + 2) * sizeof(int));
    short* W1h = (short*)alloc(16384 * sizeof(short));
    short* W1l = (short*)alloc(16384 * sizeof(short));
    short* W2h = (short*)alloc(16384 * sizeof(short));
    short* W2l = (short*)alloc(16384 * sizeof(short));
    short* W3h = (short*)alloc(6144 * sizeof(short));
    short* W3l = (short*)alloc(6144 * sizeof(short));
    int*   rank = (int*)QC;
    u32x2* G1 = (u32x2*)QB;
    u32x2* G2 = (u32x2*)QC;

    const int seg = (N + SBLK - 1) / SBLK;
    const int eblocks4 = (E + 1023) / 1024;  // 4 edges/thread

    // --- CSR build ---
    hipMemsetAsync(deg, 0, (size_t)N * sizeof(int), stream);
    deg_rank_kernel<<<eblocks4, 256, 0, stream>>>(dst, deg, rank, E);
    scanA_kernel<<<SBLK, 256, 0, stream>>>(deg, rowptr, bsum, norm, N, seg);
    scanC_kernel<<<SBLK, 256, 0, stream>>>(rowptr, bsum, N, seg);
    fill_kernel<<<eblocks4, 256, 0, stream>>>(src, dst, rowptr, rank, col, E);

    // --- W fragment prep + input quantization ---
    wprep_all<<<(38912 + 255) / 256, 256, 0, stream>>>(W1, W2, W3, W1h, W1l, W2h, W2l, W3h, W3l);
    {
        int waves2 = (N + 1) / 2;
        int xblocks = (waves2 * 64 + 255) / 256;
        xquant_kernel<<<xblocks, 256, 0, stream>>>((const float4*)features, norm, QA, Snx, N);
    }

    const int spmm_blocks = (N * 64 + 255) / 256;  // one wave per node
    const int gemm_blocks = (N + 63) / 64;

    // layer 1
    spmm128_q<1><<<spmm_blocks, 256, 0, stream>>>((const u32x4*)QA, Snx, rowptr, col, norm,
                                                  (u32x4*)QB, Sk, N);
    spmm128_q<0><<<spmm_blocks, 256, 0, stream>>>((const u32x4*)QB, Sk, rowptr, col, norm,
                                                  (u32x4*)QC, Sq2, N);
    gemm_mfma128<<<gemm_blocks, 256, 0, stream>>>((const unsigned short*)QC, Sq2,
                                                  (const short8v*)W1h, (const short8v*)W1l,
                                                  b1, norm, (unsigned short*)QA, Sg, Sng, N);

    // layer 2
    spmm128_q<1><<<spmm_blocks, 256, 0, stream>>>((const u32x4*)QA, Sng, rowptr, col, norm,
                                                  (u32x4*)QB, Sk, N);
    spmm128_q<0><<<spmm_blocks, 256, 0, stream>>>((const u32x4*)QB, Sk, rowptr, col, norm,
                                                  (u32x4*)QC, Sq2, N);
    gemm_mfma128<<<gemm_blocks, 256, 0, stream>>>((const unsigned short*)QC, Sq2,
                                                  (const short8v*)W2h, (const short8v*)W2l,
                                                  b2, norm, (unsigned short*)QA, Sg, Sng, N);

    // layer 3 (reordered): project 128->40 (int16 in/out), then 2 hops at 40-wide
    gemm_mfma40<<<gemm_blocks, 256, 0, stream>>>((const unsigned short*)QA, Sg,
                                                 (const short8v*)W3h, (const short8v*)W3l,
                                                 norm, (unsigned short*)G1, S3, Sn3, N);
    spmm40_q<0><<<spmm_blocks, 256, 0, stream>>>(G1, Sn3, rowptr, col, norm,
                                                 G2, S4, nullptr, nullptr, N);
    spmm40_q<1><<<spmm_blocks, 256, 0, stream>>>(G2, S4, rowptr, col, norm,
                                                 nullptr, nullptr, (f32x4*)out, b3, N);
}